// Round 6
// baseline (403.200 us; speedup 1.0000x reference)
//
#include <hip/hip_runtime.h>
#include <math.h>

#define RQ 6               // per-lane queue depth (fallback path only)
constexpr int WRANKS = 512; // phase-1 rank window (8 chunks of 64)
constexpr int WCH = 8;

typedef __attribute__((ext_vector_type(8))) short s8v;    // 8 bf16 (4 VGPRs)
typedef __attribute__((ext_vector_type(4))) float f32x4;  // MFMA acc

__device__ inline unsigned short f2bf(float x) {          // RNE f32->bf16
    const unsigned int u = __float_as_uint(x);
    return (unsigned short)((u + 0x7FFFu + ((u >> 16) & 1u)) >> 16);
}

// N(0,1) quantiles at i/64, i=1..63. PERF-ONLY hint; CSR uses exact counts.
__constant__ float ZB[63] = {
    -2.1539f, -1.8627f, -1.6759f, -1.5341f, -1.4178f, -1.3180f, -1.2299f, -1.1503f,
    -1.0775f, -1.0100f, -0.9468f, -0.8871f, -0.8305f, -0.7764f, -0.7245f, -0.6745f,
    -0.6261f, -0.5791f, -0.5334f, -0.4888f, -0.4451f, -0.4023f, -0.3601f, -0.3186f,
    -0.2776f, -0.2372f, -0.1971f, -0.1573f, -0.1178f, -0.0784f, -0.0392f,  0.0000f,
     0.0392f,  0.0784f,  0.1178f,  0.1573f,  0.1971f,  0.2372f,  0.2776f,  0.3186f,
     0.3601f,  0.4023f,  0.4451f,  0.4888f,  0.5334f,  0.5791f,  0.6261f,  0.6745f,
     0.7245f,  0.7764f,  0.8305f,  0.8871f,  0.9468f,  1.0100f,  1.0775f,  1.1503f,
     1.2299f,  1.3180f,  1.4178f,  1.5341f,  1.6759f,  1.8627f,  2.1539f };

// ---------------------------------------------------------------------------
// K0: z-bin CSR build. One block per (b,list): count -> prefix -> scatter.
// ---------------------------------------------------------------------------
__global__ __launch_bounds__(1024) void zbin_kernel(
    const float* __restrict__ p0, const float* __restrict__ p1,
    float4* __restrict__ sp, int* __restrict__ starts, int N)
{
    __shared__ int cnt[64], off[64], cur[64];
    const int t = threadIdx.x;
    const int bl = blockIdx.x;                    // b*2 + list
    const int b = bl >> 1, list = bl & 1;
    const float* rb = (list ? p1 : p0) + (size_t)(b * 3) * N;
    if (t < 64) { cnt[t] = 0; cur[t] = 0; }
    __syncthreads();
    int mybin[4]; float mx[4], my[4], mz[4];
    for (int i = 0; i < 4; ++i) {
        const int idx = i * 1024 + t;
        const float z = rb[2 * N + idx];
        mx[i] = rb[idx]; my[i] = rb[N + idx]; mz[i] = z;
        int bin = 0;
#pragma unroll
        for (int s = 32; s; s >>= 1)
            if (bin + s <= 63 && z >= ZB[bin + s - 1]) bin += s;
        mybin[i] = bin;
        atomicAdd(&cnt[bin], 1);
    }
    __syncthreads();
    if (t < 64) {                                 // wave 0: exclusive prefix
        const int v = cnt[t];
        int x = v;
#pragma unroll
        for (int o = 1; o < 64; o <<= 1) {
            const int y = __shfl_up(x, o);
            if (t >= o) x += y;
        }
        off[t] = x - v;
        starts[bl * 65 + t] = x - v;
        if (t == 63) starts[bl * 65 + 64] = x;
    }
    __syncthreads();
    for (int i = 0; i < 4; ++i) {
        const int bin = mybin[i];
        const int pos = off[bin] + atomicAdd(&cur[bin], 1);
        sp[(size_t)bl * 4096 + pos] =
            make_float4(mx[i], my[i], mz[i],
                        fmaf(mx[i], mx[i], fmaf(my[i], my[i], mz[i] * mz[i])));
    }
}

// ---------------------------------------------------------------------------
// K0b: query gather. One thread per query; TLP hides the dependent gather
// latency (verified win in R5: FETCH_SIZE 7.39 -> 4.83 MB).
// ---------------------------------------------------------------------------
__global__ __launch_bounds__(256) void gather_kernel(
    const float* __restrict__ p0, const float* __restrict__ p1,
    const float* __restrict__ wt, const int* __restrict__ perm,
    float4* __restrict__ newp, int N)
{
    const int q = blockIdx.x * 256 + threadIdx.x;
    const int b = q / N, n = q - b * N;
    const float wt0 = wt[b * 2];
    const int N0 = (int)(N * wt0);
    int j; const float* src;
    if (n < N0) { j = perm[(b * 2) * N + n];            src = p0; }
    else        { j = perm[(b * 2 + 1) * N + (n - N0)]; src = p1; }
    newp[q] = make_float4(src[(b * 3) * N + j], src[(b * 3 + 1) * N + j],
                          src[(b * 3 + 2) * N + j], 0.f);
}

// ---------------------------------------------------------------------------
// K1 helpers
// ---------------------------------------------------------------------------

// ballot-compact step: candidates with key<=T go to LDS slots (packed u64)
__device__ __forceinline__ void cpush(unsigned key, unsigned pos, unsigned Tu,
                                      bool valid, uint2* __restrict__ cc,
                                      int& cnt)
{
    const bool pred = valid && (key <= Tu);
    const unsigned long long bal = __ballot(pred);
    const unsigned below = __builtin_amdgcn_mbcnt_hi(
        (unsigned)(bal >> 32), __builtin_amdgcn_mbcnt_lo((unsigned)bal, 0u));
    const unsigned idx = (unsigned)cnt + below;
    if (pred && idx < 64u) cc[idx] = make_uint2(key, pos);
    cnt += (int)__popcll(bal);
}

// compaction scan over an arbitrary CSR range (expansion bins / remainders)
__device__ __forceinline__ void cscan(const float4* __restrict__ L,
                                      int bs, int be,
                                      float qx, float qy, float qz, float qq,
                                      unsigned Tu, uint2* __restrict__ cc,
                                      int& cnt, int lane)
{
    for (int p = bs; p < be; p += 64) {
        const int pos = p + lane;
        const float4 pc = L[min(pos, be - 1)];
        const float dt = fmaf(qz, pc.z, fmaf(qy, pc.y, qx * pc.x));
        const float d = fmaxf(fmaf(-2.f, dt, pc.w + qq), 0.f);
        cpush(__float_as_uint(d), (unsigned)pos, Tu, pos < be, cc, cnt);
    }
}

// dual-chain 64-wide bitonic sort of both lists' candidates, write top-kk.
// Selection order (key,pos) identical to the verified pop loop.
__device__ __forceinline__ void sort2_write(
    const uint2* __restrict__ cc0, int cnt0,
    const float4* __restrict__ L0, int kk0, int ob0,
    const uint2* __restrict__ cc1, int cnt1,
    const float4* __restrict__ L1, int kk1, int ob1,
    float qx, float qy, float qz, float4* __restrict__ feat, int lane)
{
    const uint2 v0 = cc0[lane];
    const uint2 v1 = cc1[lane];
    unsigned vk0 = (lane < cnt0) ? v0.x : 0xFFFFFFFFu;
    unsigned vp0 = (lane < cnt0) ? v0.y : 0xFFFFFFFFu;
    unsigned vk1 = (lane < cnt1) ? v1.x : 0xFFFFFFFFu;
    unsigned vp1 = (lane < cnt1) ? v1.y : 0xFFFFFFFFu;
#pragma unroll
    for (int k2 = 2; k2 <= 64; k2 <<= 1) {
#pragma unroll
        for (int jj = k2 >> 1; jj; jj >>= 1) {
            const unsigned yk0 = __shfl_xor(vk0, jj), yp0 = __shfl_xor(vp0, jj);
            const unsigned yk1 = __shfl_xor(vk1, jj), yp1 = __shfl_xor(vp1, jj);
            const bool keepmin = (((lane & jj) == 0) == ((lane & k2) == 0));
            const bool lt0 = (vk0 < yk0) || ((vk0 == yk0) && (vp0 < yp0));
            const bool s0 = keepmin ? (!lt0) : lt0;
            vk0 = s0 ? yk0 : vk0; vp0 = s0 ? yp0 : vp0;
            const bool lt1 = (vk1 < yk1) || ((vk1 == yk1) && (vp1 < yp1));
            const bool s1 = keepmin ? (!lt1) : lt1;
            vk1 = s1 ? yk1 : vk1; vp1 = s1 ? yp1 : vp1;
        }
    }
    if (lane < kk0) {
        const float4 pc = L0[vp0 & 4095u];
        const float rx = pc.x - qx, ry = pc.y - qy, rz = pc.z - qz;
        feat[ob0 + lane] =
            make_float4(rx, ry, rz, sqrtf(fmaf(rx, rx, fmaf(ry, ry, rz * rz))));
    }
    if (lane < kk1) {
        const float4 pc = L1[vp1 & 4095u];
        const float rx = pc.x - qx, ry = pc.y - qy, rz = pc.z - qz;
        feat[ob1 + lane] =
            make_float4(rx, ry, rz, sqrtf(fmaf(rx, rx, fmaf(ry, ry, rz * rz))));
    }
}

// single-list sort (used only when the other list overflowed)
__device__ __forceinline__ void sort_write(
    const uint2* __restrict__ cc, int cnt,
    const float4* __restrict__ L, int kk, int obase,
    float qx, float qy, float qz, float4* __restrict__ feat, int lane)
{
    const uint2 v = cc[lane];
    unsigned vk = (lane < cnt) ? v.x : 0xFFFFFFFFu;
    unsigned vp = (lane < cnt) ? v.y : 0xFFFFFFFFu;
#pragma unroll
    for (int k2 = 2; k2 <= 64; k2 <<= 1) {
#pragma unroll
        for (int jj = k2 >> 1; jj; jj >>= 1) {
            const unsigned yk = __shfl_xor(vk, jj);
            const unsigned yp = __shfl_xor(vp, jj);
            const bool keepmin = (((lane & jj) == 0) == ((lane & k2) == 0));
            const bool lt = (vk < yk) || ((vk == yk) && (vp < yp));
            const bool sely = keepmin ? (!lt) : lt;
            vk = sely ? yk : vk;
            vp = sely ? yp : vp;
        }
    }
    if (lane < kk) {
        const float4 pc = L[vp & 4095u];
        const float rx = pc.x - qx, ry = pc.y - qy, rz = pc.z - qz;
        feat[obase + lane] =
            make_float4(rx, ry, rz, sqrtf(fmaf(rx, rx, fmaf(ry, ry, rz * rz))));
    }
}

// ---- fallback path (cnt>64, astronomically rare): full-list queue scan ----
__device__ __forceinline__ void qpush(unsigned (&kh)[RQ], unsigned (&kl)[RQ],
                                      unsigned key, unsigned pos)
{
    bool cb[RQ];
#pragma unroll
    for (int s = 0; s < RQ; ++s) cb[s] = key < kh[s];
#pragma unroll
    for (int s = RQ - 1; s >= 1; --s) {
        kh[s] = cb[s - 1] ? kh[s - 1] : (cb[s] ? key : kh[s]);
        kl[s] = cb[s - 1] ? kl[s - 1] : (cb[s] ? pos : kl[s]);
    }
    kh[0] = cb[0] ? key : kh[0];
    kl[0] = cb[0] ? pos : kl[0];
}

__device__ __forceinline__ void pop_extract(
    unsigned (&kh)[RQ], unsigned (&kl)[RQ], int kk,
    const float4* __restrict__ L, int obase,
    float qx, float qy, float qz, float4* __restrict__ feat, int lane)
{
    unsigned mwin = 0;
    for (int rr = 0; rr < kk; ++rr) {
        unsigned gg = kh[0];
#pragma unroll
        for (int off = 32; off; off >>= 1) gg = min(gg, __shfl_xor(gg, off));
        const bool tied = (kh[0] == gg);
        unsigned mc;
        const unsigned long long bal = __ballot(tied);
        if (bal & (bal - 1)) {
            mc = tied ? kl[0] : 0xFFFFFFFFu;
#pragma unroll
            for (int off = 32; off; off >>= 1) mc = min(mc, __shfl_xor(mc, off));
        } else {
            mc = __shfl(kl[0], (int)__ffsll((long long)bal) - 1);
        }
        const bool w = tied && (kl[0] == mc);
        if (lane == rr) mwin = mc;
#pragma unroll
        for (int s = 0; s < RQ - 1; ++s) {
            kh[s] = w ? kh[s + 1] : kh[s];
            kl[s] = w ? kl[s + 1] : kl[s];
        }
        kh[RQ - 1] = w ? 0xFFFFFFFFu : kh[RQ - 1];
        kl[RQ - 1] = w ? 0xFFFFFFFFu : kl[RQ - 1];
    }
    if (lane < kk) {
        const float4 pc = L[mwin & 4095u];
        const float rx = pc.x - qx, ry = pc.y - qy, rz = pc.z - qz;
        feat[obase + lane] =
            make_float4(rx, ry, rz, sqrtf(fmaf(rx, rx, fmaf(ry, ry, rz * rz))));
    }
}

__device__ __forceinline__ void fallback_full(
    const float4* __restrict__ L, int Npts, int kk, int obase,
    float qx, float qy, float qz, float qq,
    float4* __restrict__ feat, int lane)
{
    unsigned kh[RQ], kl[RQ];
#pragma unroll
    for (int s = 0; s < RQ; ++s) { kh[s] = 0xFFFFFFFFu; kl[s] = 0xFFFFFFFFu; }
    for (int p = 0; p < Npts; p += 64) {
        const int pos = p + lane;
        const float4 pc = L[min(pos, Npts - 1)];
        const float dt = fmaf(qz, pc.z, fmaf(qy, pc.y, qx * pc.x));
        const float d = fmaxf(fmaf(-2.f, dt, pc.w + qq), 0.f);
        const unsigned key = (pos < Npts) ? __float_as_uint(d) : 0xFFFFFFFFu;
        qpush(kh, kl, key, (unsigned)pos);
    }
    pop_extract(kh, kl, kk, L, obase, qx, qy, qz, feat, lane);
}

// ---------------------------------------------------------------------------
// K1: exact kNN. One wave per query pair {(b,0,n),(b,1,n)} (kk0+kk1=32).
// R6: R4's verified bitonic-selection structure, plus (a) hoisted query
// gather (gather_kernel, R5's verified FETCH win), (b) rank window shrunk
// 768->512 (expected candidate count is window-invariant (~29), so T quality
// and overflow safety unchanged), (c) all 16 chunk loads issued up front for
// maximum memory-level parallelism, (d) packed uint2 LDS compaction.
// Exactness: window + remainders + bin-edge-dz^2 expansion covers all points;
// selection by (key,pos) identical to the verified pop loop; cnt>64 -> exact
// full-scan fallback.
// ---------------------------------------------------------------------------
__global__ __launch_bounds__(256, 4) void knn_kernel(
    const float* __restrict__ wt,
    const float4* __restrict__ sp, const int* __restrict__ starts,
    float4* __restrict__ feat, const float4* __restrict__ newp, int N)
{
    __shared__ uint2 cc0s[256], cc1s[256];
    const int lane = threadIdx.x & 63;
    const int wv = threadIdx.x >> 6;
    const int gwave = (int)((blockIdx.x * 256 + threadIdx.x) >> 6); // pair id
    const int b = gwave / N;
    const int n = gwave - b * N;
    const int q = b * N + n;

    uint2* __restrict__ cc0 = cc0s + wv * 64;
    uint2* __restrict__ cc1 = cc1s + wv * 64;

    const float wt0 = __uint_as_float(__builtin_amdgcn_readfirstlane(
                          __float_as_uint(wt[b * 2])));
    const int k0 = (int)(32 * wt0);
    const int kk0 = k0, kk1 = 32 - k0;            // both in [8,24]

    const float4 qp = newp[q];                    // broadcast load
    const float qx = __uint_as_float(__builtin_amdgcn_readfirstlane(__float_as_uint(qp.x)));
    const float qy = __uint_as_float(__builtin_amdgcn_readfirstlane(__float_as_uint(qp.y)));
    const float qz = __uint_as_float(__builtin_amdgcn_readfirstlane(__float_as_uint(qp.z)));
    const float qq = qx * qx + qy * qy + qz * qz;

    const int bl0 = b * 2, bl1 = b * 2 + 1;
    const int stv0 = starts[bl0 * 65 + lane];     // lane j holds starts[j]
    const int stv1 = starts[bl1 * 65 + lane];

    // query bin via one ballot over the constant boundary table
    const float bv = (lane < 63) ? ZB[lane] : 3.0e38f;
    const int qbin = __popcll(__ballot(qz >= bv));    // 0..63

    const float4* L0 = sp + (size_t)bl0 * 4096;
    const float4* L1 = sp + (size_t)bl1 * 4096;

    // rank windows centered on the query bin's rank midpoint
    const int st0 = __shfl(stv0, qbin);
    const int en0 = (qbin >= 63) ? N : __shfl(stv0, qbin + 1);
    const int st1 = __shfl(stv1, qbin);
    const int en1 = (qbin >= 63) ? N : __shfl(stv1, qbin + 1);
    int s0 = ((st0 + en0) >> 1) - WRANKS / 2;
    s0 = s0 < 0 ? 0 : (s0 > N - WRANKS ? N - WRANKS : s0);
    int s1 = ((st1 + en1) >> 1) - WRANKS / 2;
    s1 = s1 < 0 ? 0 : (s1 > N - WRANKS ? N - WRANKS : s1);
    const int e0 = s0 + WRANKS, e1 = s1 + WRANKS;

    // ---- pass A: all 16 chunk loads issued up front (max MLP) ----
    const float4* Lb0 = L0 + s0 + lane;
    const float4* Lb1 = L1 + s1 + lane;
    float4 P0v[WCH], P1v[WCH];
#pragma unroll
    for (int c = 0; c < WCH; ++c) P0v[c] = Lb0[c << 6];
#pragma unroll
    for (int c = 0; c < WCH; ++c) P1v[c] = Lb1[c << 6];

    unsigned k0v[WCH], k1v[WCH];
    unsigned mn0 = 0xFFFFFFFFu, mn1 = 0xFFFFFFFFu;
#pragma unroll
    for (int c = 0; c < WCH; ++c) {
        const float dt0 = fmaf(qz, P0v[c].z, fmaf(qy, P0v[c].y, qx * P0v[c].x));
        k0v[c] = __float_as_uint(fmaxf(fmaf(-2.f, dt0, P0v[c].w + qq), 0.f));
        mn0 = min(mn0, k0v[c]);
        const float dt1 = fmaf(qz, P1v[c].z, fmaf(qy, P1v[c].y, qx * P1v[c].x));
        k1v[c] = __float_as_uint(fmaxf(fmaf(-2.f, dt1, P1v[c].w + qq), 0.f));
        mn1 = min(mn1, k1v[c]);
    }

    // ---- T = m_(kk): dual-chain wave bitonic sort of the 64 lane-mins ----
    unsigned x0 = mn0, x1 = mn1;
#pragma unroll
    for (int k2 = 2; k2 <= 64; k2 <<= 1) {
#pragma unroll
        for (int jj = k2 >> 1; jj; jj >>= 1) {
            const unsigned y0 = __shfl_xor(x0, jj);
            const unsigned y1 = __shfl_xor(x1, jj);
            const bool keepmin = (((lane & jj) == 0) == ((lane & k2) == 0));
            x0 = keepmin ? min(x0, y0) : (x0 > y0 ? x0 : y0);
            x1 = keepmin ? min(x1, y1) : (x1 > y1 ? x1 : y1);
        }
    }
    const unsigned Tu0 = (unsigned)__shfl((int)x0, kk0 - 1);
    const unsigned Tu1 = (unsigned)__shfl((int)x1, kk1 - 1);
    const float T0f = __uint_as_float(Tu0);
    const float T1f = __uint_as_float(Tu1);

    // ---- compaction from registers (no reload / recompute) ----
    int cnt0 = 0, cnt1 = 0;
#pragma unroll
    for (int ch = 0; ch < WCH; ++ch) {
        cpush(k0v[ch], (unsigned)(s0 + (ch << 6) + lane), Tu0, true, cc0, cnt0);
        cpush(k1v[ch], (unsigned)(s1 + (ch << 6) + lane), Tu1, true, cc1, cnt1);
    }

    // ---- outside the window: partial-bin remainders + bin-edge expansion ----
    {
        // list 0
        const int binL = __popcll(__ballot(stv0 <= s0)) - 1;    // bin of rank s0
        if (s0 > 0) {
            const int bs = __shfl(stv0, binL);
            if (bs < s0) cscan(L0, bs, s0, qx, qy, qz, qq, Tu0, cc0, cnt0, lane);
            for (int jb = binL - 1; jb >= 0; --jb) {
                const float dz = qz - ZB[jb];
                if (dz * dz * 0.99999f > T0f) break;
                const int bs2 = __shfl(stv0, jb);
                const int be2 = __shfl(stv0, jb + 1);
                cscan(L0, bs2, be2, qx, qy, qz, qq, Tu0, cc0, cnt0, lane);
            }
        }
        if (e0 < N) {
            const int binR = __popcll(__ballot(stv0 <= e0)) - 1; // bin of rank e0
            const int re = (binR >= 63) ? N : __shfl(stv0, binR + 1);
            if (e0 < re) cscan(L0, e0, re, qx, qy, qz, qq, Tu0, cc0, cnt0, lane);
            for (int jb = binR + 1; jb <= 63; ++jb) {
                const float dz = ZB[jb - 1] - qz;
                if (dz * dz * 0.99999f > T0f) break;
                const int bs2 = __shfl(stv0, jb);
                const int be2 = (jb >= 63) ? N : __shfl(stv0, jb + 1);
                cscan(L0, bs2, be2, qx, qy, qz, qq, Tu0, cc0, cnt0, lane);
            }
        }
        // list 1
        const int binL1 = __popcll(__ballot(stv1 <= s1)) - 1;
        if (s1 > 0) {
            const int bs = __shfl(stv1, binL1);
            if (bs < s1) cscan(L1, bs, s1, qx, qy, qz, qq, Tu1, cc1, cnt1, lane);
            for (int jb = binL1 - 1; jb >= 0; --jb) {
                const float dz = qz - ZB[jb];
                if (dz * dz * 0.99999f > T1f) break;
                const int bs2 = __shfl(stv1, jb);
                const int be2 = __shfl(stv1, jb + 1);
                cscan(L1, bs2, be2, qx, qy, qz, qq, Tu1, cc1, cnt1, lane);
            }
        }
        if (e1 < N) {
            const int binR1 = __popcll(__ballot(stv1 <= e1)) - 1;
            const int re = (binR1 >= 63) ? N : __shfl(stv1, binR1 + 1);
            if (e1 < re) cscan(L1, e1, re, qx, qy, qz, qq, Tu1, cc1, cnt1, lane);
            for (int jb = binR1 + 1; jb <= 63; ++jb) {
                const float dz = ZB[jb - 1] - qz;
                if (dz * dz * 0.99999f > T1f) break;
                const int bs2 = __shfl(stv1, jb);
                const int be2 = (jb >= 63) ? N : __shfl(stv1, jb + 1);
                cscan(L1, bs2, be2, qx, qy, qz, qq, Tu1, cc1, cnt1, lane);
            }
        }
    }

    // ---- finalize: dual-chain sort, write top-kk (fallback if overflow) ----
    const int ob0 = (q << 5), ob1 = (q << 5) + k0;
    if ((cnt0 <= 64) && (cnt1 <= 64)) {
        sort2_write(cc0, cnt0, L0, kk0, ob0,
                    cc1, cnt1, L1, kk1, ob1,
                    qx, qy, qz, feat, lane);
    } else {
        if (cnt0 <= 64) sort_write(cc0, cnt0, L0, kk0, ob0, qx, qy, qz, feat, lane);
        else            fallback_full(L0, N, kk0, ob0, qx, qy, qz, qq, feat, lane);
        if (cnt1 <= 64) sort_write(cc1, cnt1, L1, kk1, ob1, qx, qy, qz, feat, lane);
        else            fallback_full(L1, N, kk1, ob1, qx, qy, qz, qq, feat, lane);
    }
}

// ---------------------------------------------------------------------------
// K2: per-sample feature moments (S=sum f [4], M=sum f f^T [10]).
// ---------------------------------------------------------------------------
__global__ __launch_bounds__(256) void moment_stats_kernel(
    const float4* __restrict__ feat, float* __restrict__ stats1, int N)
{
    const int t = threadIdx.x, lane = t & 63;
    const int bpb = 64;
    const int b = blockIdx.x / bpb;
    const int ppb = (N * 32) / bpb;
    const size_t base = (size_t)b * N * 32 + (size_t)(blockIdx.x % bpb) * ppb;
    float a[14];
#pragma unroll
    for (int i = 0; i < 14; ++i) a[i] = 0.f;
    for (int i = t; i < ppb; i += 256) {
        const float4 f = feat[base + i];
        a[0] += f.x; a[1] += f.y; a[2] += f.z; a[3] += f.w;
        a[4] = fmaf(f.x, f.x, a[4]);  a[5] = fmaf(f.x, f.y, a[5]);
        a[6] = fmaf(f.x, f.z, a[6]);  a[7] = fmaf(f.x, f.w, a[7]);
        a[8] = fmaf(f.y, f.y, a[8]);  a[9] = fmaf(f.y, f.z, a[9]);
        a[10] = fmaf(f.y, f.w, a[10]); a[11] = fmaf(f.z, f.z, a[11]);
        a[12] = fmaf(f.z, f.w, a[12]); a[13] = fmaf(f.w, f.w, a[13]);
    }
#pragma unroll
    for (int i = 0; i < 14; ++i) {
        float x = a[i];
#pragma unroll
        for (int o = 32; o; o >>= 1) x += __shfl_down(x, o);
        a[i] = x;
    }
    __shared__ float sm[14];
    if (t < 14) sm[t] = 0.f;
    __syncthreads();
    if (lane == 0) {
#pragma unroll
        for (int i = 0; i < 14; ++i) atomicAdd(&sm[i], a[i]);
    }
    __syncthreads();
    if (t < 14) atomicAdd(&stats1[b * 14 + t], sm[t]);
}

// ---------------------------------------------------------------------------
// K3/K4: conv1+gn1+relu -> bf16 h in LDS -> conv2 via MFMA 16x16x32
// ---------------------------------------------------------------------------
template <int MODE>
__global__ __launch_bounds__(256) void conv2_pass_kernel(
    const float4* __restrict__ feat,
    const float* __restrict__ w1, const float* __restrict__ b1,
    const float* __restrict__ gn1w, const float* __restrict__ gn1b,
    const float* __restrict__ stats1,
    const float* __restrict__ w2, const float* __restrict__ b2,
    const float* __restrict__ gn2w, const float* __restrict__ gn2b,
    float* __restrict__ stats2,
    const float4* __restrict__ newp, float* __restrict__ out,
    int N, float inv_cnt)
{
    const int t = threadIdx.x, lane = t & 63, wv = t >> 6;
    const int quad = lane >> 4, col = lane & 15;
    const int bpb = (N * 32) / 512;
    const int b = blockIdx.x / bpb;
    const int pblock = (blockIdx.x - b * bpb) * 512;
    const size_t pbase = (size_t)b * N * 32 + pblock + wv * 128;

    __shared__ float sfin[24];
    __shared__ float sacc[16];
    __shared__ unsigned short h_lds[512 * 40];
    __shared__ float ssc[512];

    if (t < 16) sacc[t] = 0.f;
    if (t < 4) {
        const float cnt = (float)(N * 32);
        const float* mm = stats1 + b * 14;
        const float S0 = mm[0], S1 = mm[1], S2 = mm[2], S3 = mm[3];
        float sum = 0.f, sq = 0.f;
        for (int cch = 0; cch < 8; ++cch) {
            const int cid = t * 8 + cch;
            const float4 w = ((const float4*)w1)[cid];
            const float bb = b1[cid];
            const float ws = w.x * S0 + w.y * S1 + w.z * S2 + w.w * S3;
            const float wMw =
                w.x * w.x * mm[4] + w.y * w.y * mm[8] + w.z * w.z * mm[11] +
                w.w * w.w * mm[13] +
                2.f * (w.x * w.y * mm[5] + w.x * w.z * mm[6] + w.x * w.w * mm[7] +
                       w.y * w.z * mm[9] + w.y * w.w * mm[10] + w.z * w.w * mm[12]);
            sum += cnt * bb + ws;
            sq += cnt * bb * bb + 2.f * bb * ws + wMw;
        }
        const float mu = sum * inv_cnt, var = sq * inv_cnt - mu * mu;
        sfin[2 * t] = mu; sfin[2 * t + 1] = rsqrtf(var + 1e-5f);
    }
    if (MODE == 1 && t >= 4 && t < 12) {
        const int g = t - 4;
        const float S = stats2[b * 16 + g], Q = stats2[b * 16 + 8 + g];
        const float mu = S * inv_cnt, var = Q * inv_cnt - mu * mu;
        sfin[8 + 2 * g] = mu; sfin[8 + 2 * g + 1] = rsqrtf(var + 1e-5f);
    }
    __syncthreads();

    const int c1 = lane & 31, pt = lane >> 5;
    const float4 w1r = ((const float4*)w1)[c1];
    const float b1c = b1[c1];
    const int g1 = c1 >> 3;
    const float sc1 = sfin[2 * g1 + 1] * gn1w[c1];
    const float sh1 = gn1b[c1] - sfin[2 * g1] * sc1;

    for (int it = 0; it < 64; ++it) {
        const size_t p = pbase + it * 2;
        const float4 f = feat[p + pt];
        const float y = b1c + w1r.x * f.x + w1r.y * f.y + w1r.z * f.z + w1r.w * f.w;
        const float h = fmaxf(0.f, fmaf(y, sc1, sh1));
        h_lds[(wv * 128 + it * 2 + pt) * 40 + c1] = f2bf(h);
    }

    s8v afr[4];
#pragma unroll
    for (int T = 0; T < 4; ++T) {
        const int row = T * 16 + col;
#pragma unroll
        for (int j2 = 0; j2 < 8; ++j2)
            afr[T][j2] = (short)f2bf(w2[row * 32 + quad * 8 + j2]);
    }

    float b2v[4][4], sc2v[4][4], sh2v[4][4];
#pragma unroll
    for (int T = 0; T < 4; ++T)
#pragma unroll
        for (int r4 = 0; r4 < 4; ++r4) {
            const int cch = T * 16 + quad * 4 + r4;
            b2v[T][r4] = b2[cch];
            if (MODE == 1) {
                const int g2 = cch >> 3;
                const float sc = sfin[8 + 2 * g2 + 1] * gn2w[cch];
                sc2v[T][r4] = sc;
                sh2v[T][r4] = gn2b[cch] - sfin[8 + 2 * g2] * sc + b2[cch] * sc;
            }
        }

    float gsum[4] = {0, 0, 0, 0}, gsq[4] = {0, 0, 0, 0};

    for (int pt16 = 0; pt16 < 8; ++pt16) {
        const int row = wv * 128 + pt16 * 16 + col;
        const s8v bfr = *(const s8v*)&h_lds[row * 40 + quad * 8];
        f32x4 acc[4];
#pragma unroll
        for (int T = 0; T < 4; ++T) {
            acc[T] = (f32x4){0.f, 0.f, 0.f, 0.f};
            acc[T] = __builtin_amdgcn_mfma_f32_16x16x32_bf16(afr[T], bfr, acc[T], 0, 0, 0);
        }
        if (MODE == 0) {
#pragma unroll
            for (int T = 0; T < 4; ++T)
#pragma unroll
                for (int r4 = 0; r4 < 4; ++r4) {
                    const float v = acc[T][r4] + b2v[T][r4];
                    gsum[T] += v;
                    gsq[T] = fmaf(v, v, gsq[T]);
                }
        } else {
            float s = -3.0e38f;
#pragma unroll
            for (int T = 0; T < 4; ++T)
#pragma unroll
                for (int r4 = 0; r4 < 4; ++r4)
                    s = fmaxf(s, fmaxf(0.f, fmaf(acc[T][r4], sc2v[T][r4], sh2v[T][r4])));
            s = fmaxf(s, __shfl_xor(s, 16));
            s = fmaxf(s, __shfl_xor(s, 32));
            if (quad == 0) ssc[wv * 128 + pt16 * 16 + col] = s;
        }
    }

    if (MODE == 0) {
#pragma unroll
        for (int T = 0; T < 4; ++T) {
#pragma unroll
            for (int o = 1; o < 16; o <<= 1) {
                gsum[T] += __shfl_xor(gsum[T], o);
                gsq[T] += __shfl_xor(gsq[T], o);
            }
            gsum[T] += __shfl_xor(gsum[T], 16);
            gsq[T] += __shfl_xor(gsq[T], 16);
        }
        if (lane == 0) {
#pragma unroll
            for (int T = 0; T < 4; ++T) {
                atomicAdd(&sacc[2 * T], gsum[T]);
                atomicAdd(&sacc[8 + 2 * T], gsq[T]);
            }
        }
        if (lane == 32) {
#pragma unroll
            for (int T = 0; T < 4; ++T) {
                atomicAdd(&sacc[2 * T + 1], gsum[T]);
                atomicAdd(&sacc[8 + 2 * T + 1], gsq[T]);
            }
        }
        __syncthreads();
        if (t < 16) atomicAdd(&stats2[b * 16 + t], sacc[t]);
    } else {
        __syncthreads();
        const int qi = t >> 4, sub = t & 15;
        const int qg = (b * N * 32 + pblock) / 32 + qi;
        const int n = qg - b * N;
        const float s0 = ssc[qi * 32 + sub], s1 = ssc[qi * 32 + 16 + sub];
        float mx = fmaxf(s0, s1);
#pragma unroll
        for (int o = 8; o; o >>= 1) mx = fmaxf(mx, __shfl_xor(mx, o));
        const float e0 = __expf(s0 - mx), e1 = __expf(s1 - mx);
        float ssum = e0 + e1;
#pragma unroll
        for (int o = 8; o; o >>= 1) ssum += __shfl_xor(ssum, o);
        const float4 qc = newp[qg];
        const float4 f0 = feat[(size_t)qg * 32 + sub];
        const float4 f1 = feat[(size_t)qg * 32 + 16 + sub];
        float ax = e0 * (qc.x + f0.x) + e1 * (qc.x + f1.x);
        float ay = e0 * (qc.y + f0.y) + e1 * (qc.y + f1.y);
        float az = e0 * (qc.z + f0.z) + e1 * (qc.z + f1.z);
#pragma unroll
        for (int o = 8; o; o >>= 1) {
            ax += __shfl_xor(ax, o);
            ay += __shfl_xor(ay, o);
            az += __shfl_xor(az, o);
        }
        if (sub == 0) {
            const float inv = 1.f / ssum;
            out[(b * 3 + 0) * N + n] = ax * inv;
            out[(b * 3 + 1) * N + n] = ay * inv;
            out[(b * 3 + 2) * N + n] = az * inv;
        }
    }
}

// ---------------------------------------------------------------------------
extern "C" void kernel_launch(void* const* d_in, const int* in_sizes, int n_in,
                              void* d_out, int out_size, void* d_ws, size_t ws_size,
                              hipStream_t stream)
{
    const float* p0   = (const float*)d_in[0];
    const float* p1   = (const float*)d_in[1];
    const float* wt   = (const float*)d_in[3];
    const int*   perm = (const int*)d_in[4];
    const float* w1   = (const float*)d_in[5];
    const float* b1   = (const float*)d_in[6];
    const float* gn1w = (const float*)d_in[7];
    const float* gn1b = (const float*)d_in[8];
    const float* w2   = (const float*)d_in[9];
    const float* b2   = (const float*)d_in[10];
    const float* gn2w = (const float*)d_in[11];
    const float* gn2b = (const float*)d_in[12];
    float* out = (float*)d_out;

    const int B = in_sizes[3] / 2;
    const int N = in_sizes[0] / (3 * B);

    // workspace layout
    char* ws = (char*)d_ws;
    float4* spts = (float4*)ws;               // B*2*4096 float4 (z-binned CSR)
    size_t off = (size_t)B * 2 * 4096 * sizeof(float4);
    float4* feat = (float4*)(ws + off);       off += (size_t)B * N * 32 * sizeof(float4);
    float4* newp = (float4*)(ws + off);       off += (size_t)B * N * sizeof(float4);
    float* stats1 = (float*)(ws + off);       off += (size_t)B * 14 * sizeof(float);
    float* stats2 = (float*)(ws + off);       off += (size_t)B * 16 * sizeof(float);
    int* starts = (int*)(ws + off);           // B*2*65 CSR offsets

    hipMemsetAsync(stats1, 0, (size_t)B * 30 * sizeof(float), stream);

    const float inv_cnt = 1.f / (8.f * (float)N * 32.f);

    gather_kernel<<<(B * N) / 256, 256, 0, stream>>>(p0, p1, wt, perm, newp, N);

    zbin_kernel<<<B * 2, 1024, 0, stream>>>(p0, p1, spts, starts, N);

    // one wave per query pair -> B*N waves -> B*N/4 blocks of 256 threads
    knn_kernel<<<(B * N) / 4, 256, 0, stream>>>(
        wt, spts, starts, feat, newp, N);

    moment_stats_kernel<<<B * 64, 256, 0, stream>>>(feat, stats1, N);

    conv2_pass_kernel<0><<<(B * N * 32) / 512, 256, 0, stream>>>(
        feat, w1, b1, gn1w, gn1b, stats1, w2, b2, gn2w, gn2b, stats2,
        newp, out, N, inv_cnt);

    conv2_pass_kernel<1><<<(B * N * 32) / 512, 256, 0, stream>>>(
        feat, w1, b1, gn1w, gn1b, stats1, w2, b2, gn2w, gn2b, stats2,
        newp, out, N, inv_cnt);
}

// Round 7
// 343.546 us; speedup vs baseline: 1.1736x; 1.1736x over previous
//
#include <hip/hip_runtime.h>
#include <math.h>

#define RQ 6               // per-lane queue depth (fallback path only)
constexpr int WRANKS = 768; // phase-1 rank window (12 chunks of 64) -- R4 value
constexpr int WCH = 12;

typedef __attribute__((ext_vector_type(8))) short s8v;    // 8 bf16 (4 VGPRs)
typedef __attribute__((ext_vector_type(4))) float f32x4;  // MFMA acc

__device__ inline unsigned short f2bf(float x) {          // RNE f32->bf16
    const unsigned int u = __float_as_uint(x);
    return (unsigned short)((u + 0x7FFFu + ((u >> 16) & 1u)) >> 16);
}

// N(0,1) quantiles at i/64, i=1..63. PERF-ONLY hint; CSR uses exact counts.
__constant__ float ZB[63] = {
    -2.1539f, -1.8627f, -1.6759f, -1.5341f, -1.4178f, -1.3180f, -1.2299f, -1.1503f,
    -1.0775f, -1.0100f, -0.9468f, -0.8871f, -0.8305f, -0.7764f, -0.7245f, -0.6745f,
    -0.6261f, -0.5791f, -0.5334f, -0.4888f, -0.4451f, -0.4023f, -0.3601f, -0.3186f,
    -0.2776f, -0.2372f, -0.1971f, -0.1573f, -0.1178f, -0.0784f, -0.0392f,  0.0000f,
     0.0392f,  0.0784f,  0.1178f,  0.1573f,  0.1971f,  0.2372f,  0.2776f,  0.3186f,
     0.3601f,  0.4023f,  0.4451f,  0.4888f,  0.5334f,  0.5791f,  0.6261f,  0.6745f,
     0.7245f,  0.7764f,  0.8305f,  0.8871f,  0.9468f,  1.0100f,  1.0775f,  1.1503f,
     1.2299f,  1.3180f,  1.4178f,  1.5341f,  1.6759f,  1.8627f,  2.1539f };

// ---------------------------------------------------------------------------
// K0: z-bin CSR build. One block per (b,list): count -> prefix -> scatter.
// ---------------------------------------------------------------------------
__global__ __launch_bounds__(1024) void zbin_kernel(
    const float* __restrict__ p0, const float* __restrict__ p1,
    float4* __restrict__ sp, int* __restrict__ starts, int N)
{
    __shared__ int cnt[64], off[64], cur[64];
    const int t = threadIdx.x;
    const int bl = blockIdx.x;                    // b*2 + list
    const int b = bl >> 1, list = bl & 1;
    const float* rb = (list ? p1 : p0) + (size_t)(b * 3) * N;
    if (t < 64) { cnt[t] = 0; cur[t] = 0; }
    __syncthreads();
    int mybin[4]; float mx[4], my[4], mz[4];
    for (int i = 0; i < 4; ++i) {
        const int idx = i * 1024 + t;
        const float z = rb[2 * N + idx];
        mx[i] = rb[idx]; my[i] = rb[N + idx]; mz[i] = z;
        int bin = 0;
#pragma unroll
        for (int s = 32; s; s >>= 1)
            if (bin + s <= 63 && z >= ZB[bin + s - 1]) bin += s;
        mybin[i] = bin;
        atomicAdd(&cnt[bin], 1);
    }
    __syncthreads();
    if (t < 64) {                                 // wave 0: exclusive prefix
        const int v = cnt[t];
        int x = v;
#pragma unroll
        for (int o = 1; o < 64; o <<= 1) {
            const int y = __shfl_up(x, o);
            if (t >= o) x += y;
        }
        off[t] = x - v;
        starts[bl * 65 + t] = x - v;
        if (t == 63) starts[bl * 65 + 64] = x;
    }
    __syncthreads();
    for (int i = 0; i < 4; ++i) {
        const int bin = mybin[i];
        const int pos = off[bin] + atomicAdd(&cur[bin], 1);
        sp[(size_t)bl * 4096 + pos] =
            make_float4(mx[i], my[i], mz[i],
                        fmaf(mx[i], mx[i], fmaf(my[i], my[i], mz[i] * mz[i])));
    }
}

// ---------------------------------------------------------------------------
// K0b: query gather. One thread per query; TLP hides the dependent gather
// latency (verified: FETCH_SIZE 7.39 -> 4.83 MB in knn).
// ---------------------------------------------------------------------------
__global__ __launch_bounds__(256) void gather_kernel(
    const float* __restrict__ p0, const float* __restrict__ p1,
    const float* __restrict__ wt, const int* __restrict__ perm,
    float4* __restrict__ newp, int N)
{
    const int q = blockIdx.x * 256 + threadIdx.x;
    const int b = q / N, n = q - b * N;
    const float wt0 = wt[b * 2];
    const int N0 = (int)(N * wt0);
    int j; const float* src;
    if (n < N0) { j = perm[(b * 2) * N + n];            src = p0; }
    else        { j = perm[(b * 2 + 1) * N + (n - N0)]; src = p1; }
    newp[q] = make_float4(src[(b * 3) * N + j], src[(b * 3 + 1) * N + j],
                          src[(b * 3 + 2) * N + j], 0.f);
}

// ---------------------------------------------------------------------------
// K1 helpers
// ---------------------------------------------------------------------------

// ballot-compact step: candidates with key<=T go to LDS slots (packed u64)
__device__ __forceinline__ void cpush(unsigned key, unsigned pos, unsigned Tu,
                                      bool valid, uint2* __restrict__ cc,
                                      int& cnt)
{
    const bool pred = valid && (key <= Tu);
    const unsigned long long bal = __ballot(pred);
    const unsigned below = __builtin_amdgcn_mbcnt_hi(
        (unsigned)(bal >> 32), __builtin_amdgcn_mbcnt_lo((unsigned)bal, 0u));
    const unsigned idx = (unsigned)cnt + below;
    if (pred && idx < 64u) cc[idx] = make_uint2(key, pos);
    cnt += (int)__popcll(bal);
}

// compaction scan over an arbitrary CSR range (expansion bins / remainders)
__device__ __forceinline__ void cscan(const float4* __restrict__ L,
                                      int bs, int be,
                                      float qx, float qy, float qz, float qq,
                                      unsigned Tu, uint2* __restrict__ cc,
                                      int& cnt, int lane)
{
    for (int p = bs; p < be; p += 64) {
        const int pos = p + lane;
        const float4 pc = L[min(pos, be - 1)];
        const float dt = fmaf(qz, pc.z, fmaf(qy, pc.y, qx * pc.x));
        const float d = fmaxf(fmaf(-2.f, dt, pc.w + qq), 0.f);
        cpush(__float_as_uint(d), (unsigned)pos, Tu, pos < be, cc, cnt);
    }
}

// dual-chain 64-wide bitonic sort of both lists' candidates, write top-kk.
// Selection order (key,pos) identical to the verified pop loop.
__device__ __forceinline__ void sort2_write(
    const uint2* __restrict__ cc0, int cnt0,
    const float4* __restrict__ L0, int kk0, int ob0,
    const uint2* __restrict__ cc1, int cnt1,
    const float4* __restrict__ L1, int kk1, int ob1,
    float qx, float qy, float qz, float4* __restrict__ feat, int lane)
{
    const uint2 v0 = cc0[lane];
    const uint2 v1 = cc1[lane];
    unsigned vk0 = (lane < cnt0) ? v0.x : 0xFFFFFFFFu;
    unsigned vp0 = (lane < cnt0) ? v0.y : 0xFFFFFFFFu;
    unsigned vk1 = (lane < cnt1) ? v1.x : 0xFFFFFFFFu;
    unsigned vp1 = (lane < cnt1) ? v1.y : 0xFFFFFFFFu;
#pragma unroll
    for (int k2 = 2; k2 <= 64; k2 <<= 1) {
#pragma unroll
        for (int jj = k2 >> 1; jj; jj >>= 1) {
            const unsigned yk0 = __shfl_xor(vk0, jj), yp0 = __shfl_xor(vp0, jj);
            const unsigned yk1 = __shfl_xor(vk1, jj), yp1 = __shfl_xor(vp1, jj);
            const bool keepmin = (((lane & jj) == 0) == ((lane & k2) == 0));
            const bool lt0 = (vk0 < yk0) || ((vk0 == yk0) && (vp0 < yp0));
            const bool s0 = keepmin ? (!lt0) : lt0;
            vk0 = s0 ? yk0 : vk0; vp0 = s0 ? yp0 : vp0;
            const bool lt1 = (vk1 < yk1) || ((vk1 == yk1) && (vp1 < yp1));
            const bool s1 = keepmin ? (!lt1) : lt1;
            vk1 = s1 ? yk1 : vk1; vp1 = s1 ? yp1 : vp1;
        }
    }
    if (lane < kk0) {
        const float4 pc = L0[vp0 & 4095u];
        const float rx = pc.x - qx, ry = pc.y - qy, rz = pc.z - qz;
        feat[ob0 + lane] =
            make_float4(rx, ry, rz, sqrtf(fmaf(rx, rx, fmaf(ry, ry, rz * rz))));
    }
    if (lane < kk1) {
        const float4 pc = L1[vp1 & 4095u];
        const float rx = pc.x - qx, ry = pc.y - qy, rz = pc.z - qz;
        feat[ob1 + lane] =
            make_float4(rx, ry, rz, sqrtf(fmaf(rx, rx, fmaf(ry, ry, rz * rz))));
    }
}

// single-list sort (used only when the other list overflowed)
__device__ __forceinline__ void sort_write(
    const uint2* __restrict__ cc, int cnt,
    const float4* __restrict__ L, int kk, int obase,
    float qx, float qy, float qz, float4* __restrict__ feat, int lane)
{
    const uint2 v = cc[lane];
    unsigned vk = (lane < cnt) ? v.x : 0xFFFFFFFFu;
    unsigned vp = (lane < cnt) ? v.y : 0xFFFFFFFFu;
#pragma unroll
    for (int k2 = 2; k2 <= 64; k2 <<= 1) {
#pragma unroll
        for (int jj = k2 >> 1; jj; jj >>= 1) {
            const unsigned yk = __shfl_xor(vk, jj);
            const unsigned yp = __shfl_xor(vp, jj);
            const bool keepmin = (((lane & jj) == 0) == ((lane & k2) == 0));
            const bool lt = (vk < yk) || ((vk == yk) && (vp < yp));
            const bool sely = keepmin ? (!lt) : lt;
            vk = sely ? yk : vk;
            vp = sely ? yp : vp;
        }
    }
    if (lane < kk) {
        const float4 pc = L[vp & 4095u];
        const float rx = pc.x - qx, ry = pc.y - qy, rz = pc.z - qz;
        feat[obase + lane] =
            make_float4(rx, ry, rz, sqrtf(fmaf(rx, rx, fmaf(ry, ry, rz * rz))));
    }
}

// ---- fallback path (cnt>64, astronomically rare): full-list queue scan ----
__device__ __forceinline__ void qpush(unsigned (&kh)[RQ], unsigned (&kl)[RQ],
                                      unsigned key, unsigned pos)
{
    bool cb[RQ];
#pragma unroll
    for (int s = 0; s < RQ; ++s) cb[s] = key < kh[s];
#pragma unroll
    for (int s = RQ - 1; s >= 1; --s) {
        kh[s] = cb[s - 1] ? kh[s - 1] : (cb[s] ? key : kh[s]);
        kl[s] = cb[s - 1] ? kl[s - 1] : (cb[s] ? pos : kl[s]);
    }
    kh[0] = cb[0] ? key : kh[0];
    kl[0] = cb[0] ? pos : kl[0];
}

__device__ __forceinline__ void pop_extract(
    unsigned (&kh)[RQ], unsigned (&kl)[RQ], int kk,
    const float4* __restrict__ L, int obase,
    float qx, float qy, float qz, float4* __restrict__ feat, int lane)
{
    unsigned mwin = 0;
    for (int rr = 0; rr < kk; ++rr) {
        unsigned gg = kh[0];
#pragma unroll
        for (int off = 32; off; off >>= 1) gg = min(gg, __shfl_xor(gg, off));
        const bool tied = (kh[0] == gg);
        unsigned mc;
        const unsigned long long bal = __ballot(tied);
        if (bal & (bal - 1)) {
            mc = tied ? kl[0] : 0xFFFFFFFFu;
#pragma unroll
            for (int off = 32; off; off >>= 1) mc = min(mc, __shfl_xor(mc, off));
        } else {
            mc = __shfl(kl[0], (int)__ffsll((long long)bal) - 1);
        }
        const bool w = tied && (kl[0] == mc);
        if (lane == rr) mwin = mc;
#pragma unroll
        for (int s = 0; s < RQ - 1; ++s) {
            kh[s] = w ? kh[s + 1] : kh[s];
            kl[s] = w ? kl[s + 1] : kl[s];
        }
        kh[RQ - 1] = w ? 0xFFFFFFFFu : kh[RQ - 1];
        kl[RQ - 1] = w ? 0xFFFFFFFFu : kl[RQ - 1];
    }
    if (lane < kk) {
        const float4 pc = L[mwin & 4095u];
        const float rx = pc.x - qx, ry = pc.y - qy, rz = pc.z - qz;
        feat[obase + lane] =
            make_float4(rx, ry, rz, sqrtf(fmaf(rx, rx, fmaf(ry, ry, rz * rz))));
    }
}

__device__ __forceinline__ void fallback_full(
    const float4* __restrict__ L, int Npts, int kk, int obase,
    float qx, float qy, float qz, float qq,
    float4* __restrict__ feat, int lane)
{
    unsigned kh[RQ], kl[RQ];
#pragma unroll
    for (int s = 0; s < RQ; ++s) { kh[s] = 0xFFFFFFFFu; kl[s] = 0xFFFFFFFFu; }
    for (int p = 0; p < Npts; p += 64) {
        const int pos = p + lane;
        const float4 pc = L[min(pos, Npts - 1)];
        const float dt = fmaf(qz, pc.z, fmaf(qy, pc.y, qx * pc.x));
        const float d = fmaxf(fmaf(-2.f, dt, pc.w + qq), 0.f);
        const unsigned key = (pos < Npts) ? __float_as_uint(d) : 0xFFFFFFFFu;
        qpush(kh, kl, key, (unsigned)pos);
    }
    pop_extract(kh, kl, kk, L, obase, qx, qy, qz, feat, lane);
}

// ---------------------------------------------------------------------------
// K1: exact kNN. One wave per query pair {(b,0,n),(b,1,n)} (kk0+kk1=32).
// R7 = R4's verified structure (W=768, 12 static chunks, 3-stage pipelined
// pass A, dual-chain bitonic T + final sort, register-sourced compaction)
// + ONLY the two independently-verified deltas: hoisted query gather
// (broadcast newp load) and packed uint2 LDS compaction. W=512 (R6) is
// reverted: it pushed ~4 bins/list/pair from the cheap static path into the
// expensive dynamic cscan path (+36% VALU cycles, measured).
// Exactness: window + remainders + bin-edge-dz^2 expansion covers all
// points; selection by (key,pos) identical to the verified pop loop;
// cnt>64 -> exact full-scan fallback.
// ---------------------------------------------------------------------------
__global__ __launch_bounds__(256, 4) void knn_kernel(
    const float* __restrict__ wt,
    const float4* __restrict__ sp, const int* __restrict__ starts,
    float4* __restrict__ feat, const float4* __restrict__ newp, int N)
{
    __shared__ uint2 cc0s[256], cc1s[256];
    const int lane = threadIdx.x & 63;
    const int wv = threadIdx.x >> 6;
    const int gwave = (int)((blockIdx.x * 256 + threadIdx.x) >> 6); // pair id
    const int b = gwave / N;
    const int n = gwave - b * N;
    const int q = b * N + n;

    uint2* __restrict__ cc0 = cc0s + wv * 64;
    uint2* __restrict__ cc1 = cc1s + wv * 64;

    const float wt0 = __uint_as_float(__builtin_amdgcn_readfirstlane(
                          __float_as_uint(wt[b * 2])));
    const int k0 = (int)(32 * wt0);
    const int kk0 = k0, kk1 = 32 - k0;            // both in [8,24]

    const float4 qp = newp[q];                    // broadcast load
    const float qx = __uint_as_float(__builtin_amdgcn_readfirstlane(__float_as_uint(qp.x)));
    const float qy = __uint_as_float(__builtin_amdgcn_readfirstlane(__float_as_uint(qp.y)));
    const float qz = __uint_as_float(__builtin_amdgcn_readfirstlane(__float_as_uint(qp.z)));
    const float qq = qx * qx + qy * qy + qz * qz;

    const int bl0 = b * 2, bl1 = b * 2 + 1;
    const int stv0 = starts[bl0 * 65 + lane];     // lane j holds starts[j]
    const int stv1 = starts[bl1 * 65 + lane];

    // query bin via one ballot over the constant boundary table
    const float bv = (lane < 63) ? ZB[lane] : 3.0e38f;
    const int qbin = __popcll(__ballot(qz >= bv));    // 0..63

    const float4* L0 = sp + (size_t)bl0 * 4096;
    const float4* L1 = sp + (size_t)bl1 * 4096;

    // rank windows centered on the query bin's rank midpoint
    const int st0 = __shfl(stv0, qbin);
    const int en0 = (qbin >= 63) ? N : __shfl(stv0, qbin + 1);
    const int st1 = __shfl(stv1, qbin);
    const int en1 = (qbin >= 63) ? N : __shfl(stv1, qbin + 1);
    int s0 = ((st0 + en0) >> 1) - WRANKS / 2;
    s0 = s0 < 0 ? 0 : (s0 > N - WRANKS ? N - WRANKS : s0);
    int s1 = ((st1 + en1) >> 1) - WRANKS / 2;
    s1 = s1 < 0 ? 0 : (s1 > N - WRANKS ? N - WRANKS : s1);
    const int e0 = s0 + WRANKS, e1 = s1 + WRANKS;

    // ---- pass A: 12 static chunks per list, 3-stage pipeline (R4) ----
    const float4* Lb0 = L0 + s0 + lane;
    const float4* Lb1 = L1 + s1 + lane;
    unsigned k0v[WCH], k1v[WCH];
    unsigned mn0 = 0xFFFFFFFFu, mn1 = 0xFFFFFFFFu;
    {
        float4 A0[3], A1[3], B0[3], B1[3];
#pragma unroll
        for (int c = 0; c < 3; ++c) { A0[c] = Lb0[c << 6]; A1[c] = Lb1[c << 6]; }
#pragma unroll
        for (int g = 0; g < 4; ++g) {
            if (g < 3) {
#pragma unroll
                for (int c = 0; c < 3; ++c) {
                    B0[c] = Lb0[(g * 3 + 3 + c) << 6];
                    B1[c] = Lb1[(g * 3 + 3 + c) << 6];
                }
            }
#pragma unroll
            for (int c = 0; c < 3; ++c) {
                const int ch = g * 3 + c;
                {
                    const float dt = fmaf(qz, A0[c].z, fmaf(qy, A0[c].y, qx * A0[c].x));
                    k0v[ch] = __float_as_uint(fmaxf(fmaf(-2.f, dt, A0[c].w + qq), 0.f));
                    mn0 = min(mn0, k0v[ch]);
                }
                {
                    const float dt = fmaf(qz, A1[c].z, fmaf(qy, A1[c].y, qx * A1[c].x));
                    k1v[ch] = __float_as_uint(fmaxf(fmaf(-2.f, dt, A1[c].w + qq), 0.f));
                    mn1 = min(mn1, k1v[ch]);
                }
            }
            if (g < 3) {
#pragma unroll
                for (int c = 0; c < 3; ++c) { A0[c] = B0[c]; A1[c] = B1[c]; }
            }
        }
    }

    // ---- T = m_(kk): dual-chain wave bitonic sort of the 64 lane-mins ----
    unsigned x0 = mn0, x1 = mn1;
#pragma unroll
    for (int k2 = 2; k2 <= 64; k2 <<= 1) {
#pragma unroll
        for (int jj = k2 >> 1; jj; jj >>= 1) {
            const unsigned y0 = __shfl_xor(x0, jj);
            const unsigned y1 = __shfl_xor(x1, jj);
            const bool keepmin = (((lane & jj) == 0) == ((lane & k2) == 0));
            x0 = keepmin ? min(x0, y0) : (x0 > y0 ? x0 : y0);
            x1 = keepmin ? min(x1, y1) : (x1 > y1 ? x1 : y1);
        }
    }
    const unsigned Tu0 = (unsigned)__shfl((int)x0, kk0 - 1);
    const unsigned Tu1 = (unsigned)__shfl((int)x1, kk1 - 1);
    const float T0f = __uint_as_float(Tu0);
    const float T1f = __uint_as_float(Tu1);

    // ---- compaction from registers (no reload / recompute) ----
    int cnt0 = 0, cnt1 = 0;
#pragma unroll
    for (int ch = 0; ch < WCH; ++ch) {
        cpush(k0v[ch], (unsigned)(s0 + (ch << 6) + lane), Tu0, true, cc0, cnt0);
        cpush(k1v[ch], (unsigned)(s1 + (ch << 6) + lane), Tu1, true, cc1, cnt1);
    }

    // ---- outside the window: partial-bin remainders + bin-edge expansion ----
    {
        // list 0
        const int binL = __popcll(__ballot(stv0 <= s0)) - 1;    // bin of rank s0
        if (s0 > 0) {
            const int bs = __shfl(stv0, binL);
            if (bs < s0) cscan(L0, bs, s0, qx, qy, qz, qq, Tu0, cc0, cnt0, lane);
            for (int jb = binL - 1; jb >= 0; --jb) {
                const float dz = qz - ZB[jb];
                if (dz * dz * 0.99999f > T0f) break;
                const int bs2 = __shfl(stv0, jb);
                const int be2 = __shfl(stv0, jb + 1);
                cscan(L0, bs2, be2, qx, qy, qz, qq, Tu0, cc0, cnt0, lane);
            }
        }
        if (e0 < N) {
            const int binR = __popcll(__ballot(stv0 <= e0)) - 1; // bin of rank e0
            const int re = (binR >= 63) ? N : __shfl(stv0, binR + 1);
            if (e0 < re) cscan(L0, e0, re, qx, qy, qz, qq, Tu0, cc0, cnt0, lane);
            for (int jb = binR + 1; jb <= 63; ++jb) {
                const float dz = ZB[jb - 1] - qz;
                if (dz * dz * 0.99999f > T0f) break;
                const int bs2 = __shfl(stv0, jb);
                const int be2 = (jb >= 63) ? N : __shfl(stv0, jb + 1);
                cscan(L0, bs2, be2, qx, qy, qz, qq, Tu0, cc0, cnt0, lane);
            }
        }
        // list 1
        const int binL1 = __popcll(__ballot(stv1 <= s1)) - 1;
        if (s1 > 0) {
            const int bs = __shfl(stv1, binL1);
            if (bs < s1) cscan(L1, bs, s1, qx, qy, qz, qq, Tu1, cc1, cnt1, lane);
            for (int jb = binL1 - 1; jb >= 0; --jb) {
                const float dz = qz - ZB[jb];
                if (dz * dz * 0.99999f > T1f) break;
                const int bs2 = __shfl(stv1, jb);
                const int be2 = __shfl(stv1, jb + 1);
                cscan(L1, bs2, be2, qx, qy, qz, qq, Tu1, cc1, cnt1, lane);
            }
        }
        if (e1 < N) {
            const int binR1 = __popcll(__ballot(stv1 <= e1)) - 1;
            const int re = (binR1 >= 63) ? N : __shfl(stv1, binR1 + 1);
            if (e1 < re) cscan(L1, e1, re, qx, qy, qz, qq, Tu1, cc1, cnt1, lane);
            for (int jb = binR1 + 1; jb <= 63; ++jb) {
                const float dz = ZB[jb - 1] - qz;
                if (dz * dz * 0.99999f > T1f) break;
                const int bs2 = __shfl(stv1, jb);
                const int be2 = (jb >= 63) ? N : __shfl(stv1, jb + 1);
                cscan(L1, bs2, be2, qx, qy, qz, qq, Tu1, cc1, cnt1, lane);
            }
        }
    }

    // ---- finalize: dual-chain sort, write top-kk (fallback if overflow) ----
    const int ob0 = (q << 5), ob1 = (q << 5) + k0;
    if ((cnt0 <= 64) && (cnt1 <= 64)) {
        sort2_write(cc0, cnt0, L0, kk0, ob0,
                    cc1, cnt1, L1, kk1, ob1,
                    qx, qy, qz, feat, lane);
    } else {
        if (cnt0 <= 64) sort_write(cc0, cnt0, L0, kk0, ob0, qx, qy, qz, feat, lane);
        else            fallback_full(L0, N, kk0, ob0, qx, qy, qz, qq, feat, lane);
        if (cnt1 <= 64) sort_write(cc1, cnt1, L1, kk1, ob1, qx, qy, qz, feat, lane);
        else            fallback_full(L1, N, kk1, ob1, qx, qy, qz, qq, feat, lane);
    }
}

// ---------------------------------------------------------------------------
// K2: per-sample feature moments (S=sum f [4], M=sum f f^T [10]).
// ---------------------------------------------------------------------------
__global__ __launch_bounds__(256) void moment_stats_kernel(
    const float4* __restrict__ feat, float* __restrict__ stats1, int N)
{
    const int t = threadIdx.x, lane = t & 63;
    const int bpb = 64;
    const int b = blockIdx.x / bpb;
    const int ppb = (N * 32) / bpb;
    const size_t base = (size_t)b * N * 32 + (size_t)(blockIdx.x % bpb) * ppb;
    float a[14];
#pragma unroll
    for (int i = 0; i < 14; ++i) a[i] = 0.f;
    for (int i = t; i < ppb; i += 256) {
        const float4 f = feat[base + i];
        a[0] += f.x; a[1] += f.y; a[2] += f.z; a[3] += f.w;
        a[4] = fmaf(f.x, f.x, a[4]);  a[5] = fmaf(f.x, f.y, a[5]);
        a[6] = fmaf(f.x, f.z, a[6]);  a[7] = fmaf(f.x, f.w, a[7]);
        a[8] = fmaf(f.y, f.y, a[8]);  a[9] = fmaf(f.y, f.z, a[9]);
        a[10] = fmaf(f.y, f.w, a[10]); a[11] = fmaf(f.z, f.z, a[11]);
        a[12] = fmaf(f.z, f.w, a[12]); a[13] = fmaf(f.w, f.w, a[13]);
    }
#pragma unroll
    for (int i = 0; i < 14; ++i) {
        float x = a[i];
#pragma unroll
        for (int o = 32; o; o >>= 1) x += __shfl_down(x, o);
        a[i] = x;
    }
    __shared__ float sm[14];
    if (t < 14) sm[t] = 0.f;
    __syncthreads();
    if (lane == 0) {
#pragma unroll
        for (int i = 0; i < 14; ++i) atomicAdd(&sm[i], a[i]);
    }
    __syncthreads();
    if (t < 14) atomicAdd(&stats1[b * 14 + t], sm[t]);
}

// ---------------------------------------------------------------------------
// K3/K4: conv1+gn1+relu -> bf16 h in LDS -> conv2 via MFMA 16x16x32
// ---------------------------------------------------------------------------
template <int MODE>
__global__ __launch_bounds__(256) void conv2_pass_kernel(
    const float4* __restrict__ feat,
    const float* __restrict__ w1, const float* __restrict__ b1,
    const float* __restrict__ gn1w, const float* __restrict__ gn1b,
    const float* __restrict__ stats1,
    const float* __restrict__ w2, const float* __restrict__ b2,
    const float* __restrict__ gn2w, const float* __restrict__ gn2b,
    float* __restrict__ stats2,
    const float4* __restrict__ newp, float* __restrict__ out,
    int N, float inv_cnt)
{
    const int t = threadIdx.x, lane = t & 63, wv = t >> 6;
    const int quad = lane >> 4, col = lane & 15;
    const int bpb = (N * 32) / 512;
    const int b = blockIdx.x / bpb;
    const int pblock = (blockIdx.x - b * bpb) * 512;
    const size_t pbase = (size_t)b * N * 32 + pblock + wv * 128;

    __shared__ float sfin[24];
    __shared__ float sacc[16];
    __shared__ unsigned short h_lds[512 * 40];
    __shared__ float ssc[512];

    if (t < 16) sacc[t] = 0.f;
    if (t < 4) {
        const float cnt = (float)(N * 32);
        const float* mm = stats1 + b * 14;
        const float S0 = mm[0], S1 = mm[1], S2 = mm[2], S3 = mm[3];
        float sum = 0.f, sq = 0.f;
        for (int cch = 0; cch < 8; ++cch) {
            const int cid = t * 8 + cch;
            const float4 w = ((const float4*)w1)[cid];
            const float bb = b1[cid];
            const float ws = w.x * S0 + w.y * S1 + w.z * S2 + w.w * S3;
            const float wMw =
                w.x * w.x * mm[4] + w.y * w.y * mm[8] + w.z * w.z * mm[11] +
                w.w * w.w * mm[13] +
                2.f * (w.x * w.y * mm[5] + w.x * w.z * mm[6] + w.x * w.w * mm[7] +
                       w.y * w.z * mm[9] + w.y * w.w * mm[10] + w.z * w.w * mm[12]);
            sum += cnt * bb + ws;
            sq += cnt * bb * bb + 2.f * bb * ws + wMw;
        }
        const float mu = sum * inv_cnt, var = sq * inv_cnt - mu * mu;
        sfin[2 * t] = mu; sfin[2 * t + 1] = rsqrtf(var + 1e-5f);
    }
    if (MODE == 1 && t >= 4 && t < 12) {
        const int g = t - 4;
        const float S = stats2[b * 16 + g], Q = stats2[b * 16 + 8 + g];
        const float mu = S * inv_cnt, var = Q * inv_cnt - mu * mu;
        sfin[8 + 2 * g] = mu; sfin[8 + 2 * g + 1] = rsqrtf(var + 1e-5f);
    }
    __syncthreads();

    const int c1 = lane & 31, pt = lane >> 5;
    const float4 w1r = ((const float4*)w1)[c1];
    const float b1c = b1[c1];
    const int g1 = c1 >> 3;
    const float sc1 = sfin[2 * g1 + 1] * gn1w[c1];
    const float sh1 = gn1b[c1] - sfin[2 * g1] * sc1;

    for (int it = 0; it < 64; ++it) {
        const size_t p = pbase + it * 2;
        const float4 f = feat[p + pt];
        const float y = b1c + w1r.x * f.x + w1r.y * f.y + w1r.z * f.z + w1r.w * f.w;
        const float h = fmaxf(0.f, fmaf(y, sc1, sh1));
        h_lds[(wv * 128 + it * 2 + pt) * 40 + c1] = f2bf(h);
    }

    s8v afr[4];
#pragma unroll
    for (int T = 0; T < 4; ++T) {
        const int row = T * 16 + col;
#pragma unroll
        for (int j2 = 0; j2 < 8; ++j2)
            afr[T][j2] = (short)f2bf(w2[row * 32 + quad * 8 + j2]);
    }

    float b2v[4][4], sc2v[4][4], sh2v[4][4];
#pragma unroll
    for (int T = 0; T < 4; ++T)
#pragma unroll
        for (int r4 = 0; r4 < 4; ++r4) {
            const int cch = T * 16 + quad * 4 + r4;
            b2v[T][r4] = b2[cch];
            if (MODE == 1) {
                const int g2 = cch >> 3;
                const float sc = sfin[8 + 2 * g2 + 1] * gn2w[cch];
                sc2v[T][r4] = sc;
                sh2v[T][r4] = gn2b[cch] - sfin[8 + 2 * g2] * sc + b2[cch] * sc;
            }
        }

    float gsum[4] = {0, 0, 0, 0}, gsq[4] = {0, 0, 0, 0};

    for (int pt16 = 0; pt16 < 8; ++pt16) {
        const int row = wv * 128 + pt16 * 16 + col;
        const s8v bfr = *(const s8v*)&h_lds[row * 40 + quad * 8];
        f32x4 acc[4];
#pragma unroll
        for (int T = 0; T < 4; ++T) {
            acc[T] = (f32x4){0.f, 0.f, 0.f, 0.f};
            acc[T] = __builtin_amdgcn_mfma_f32_16x16x32_bf16(afr[T], bfr, acc[T], 0, 0, 0);
        }
        if (MODE == 0) {
#pragma unroll
            for (int T = 0; T < 4; ++T)
#pragma unroll
                for (int r4 = 0; r4 < 4; ++r4) {
                    const float v = acc[T][r4] + b2v[T][r4];
                    gsum[T] += v;
                    gsq[T] = fmaf(v, v, gsq[T]);
                }
        } else {
            float s = -3.0e38f;
#pragma unroll
            for (int T = 0; T < 4; ++T)
#pragma unroll
                for (int r4 = 0; r4 < 4; ++r4)
                    s = fmaxf(s, fmaxf(0.f, fmaf(acc[T][r4], sc2v[T][r4], sh2v[T][r4])));
            s = fmaxf(s, __shfl_xor(s, 16));
            s = fmaxf(s, __shfl_xor(s, 32));
            if (quad == 0) ssc[wv * 128 + pt16 * 16 + col] = s;
        }
    }

    if (MODE == 0) {
#pragma unroll
        for (int T = 0; T < 4; ++T) {
#pragma unroll
            for (int o = 1; o < 16; o <<= 1) {
                gsum[T] += __shfl_xor(gsum[T], o);
                gsq[T] += __shfl_xor(gsq[T], o);
            }
            gsum[T] += __shfl_xor(gsum[T], 16);
            gsq[T] += __shfl_xor(gsq[T], 16);
        }
        if (lane == 0) {
#pragma unroll
            for (int T = 0; T < 4; ++T) {
                atomicAdd(&sacc[2 * T], gsum[T]);
                atomicAdd(&sacc[8 + 2 * T], gsq[T]);
            }
        }
        if (lane == 32) {
#pragma unroll
            for (int T = 0; T < 4; ++T) {
                atomicAdd(&sacc[2 * T + 1], gsum[T]);
                atomicAdd(&sacc[8 + 2 * T + 1], gsq[T]);
            }
        }
        __syncthreads();
        if (t < 16) atomicAdd(&stats2[b * 16 + t], sacc[t]);
    } else {
        __syncthreads();
        const int qi = t >> 4, sub = t & 15;
        const int qg = (b * N * 32 + pblock) / 32 + qi;
        const int n = qg - b * N;
        const float s0 = ssc[qi * 32 + sub], s1 = ssc[qi * 32 + 16 + sub];
        float mx = fmaxf(s0, s1);
#pragma unroll
        for (int o = 8; o; o >>= 1) mx = fmaxf(mx, __shfl_xor(mx, o));
        const float e0 = __expf(s0 - mx), e1 = __expf(s1 - mx);
        float ssum = e0 + e1;
#pragma unroll
        for (int o = 8; o; o >>= 1) ssum += __shfl_xor(ssum, o);
        const float4 qc = newp[qg];
        const float4 f0 = feat[(size_t)qg * 32 + sub];
        const float4 f1 = feat[(size_t)qg * 32 + 16 + sub];
        float ax = e0 * (qc.x + f0.x) + e1 * (qc.x + f1.x);
        float ay = e0 * (qc.y + f0.y) + e1 * (qc.y + f1.y);
        float az = e0 * (qc.z + f0.z) + e1 * (qc.z + f1.z);
#pragma unroll
        for (int o = 8; o; o >>= 1) {
            ax += __shfl_xor(ax, o);
            ay += __shfl_xor(ay, o);
            az += __shfl_xor(az, o);
        }
        if (sub == 0) {
            const float inv = 1.f / ssum;
            out[(b * 3 + 0) * N + n] = ax * inv;
            out[(b * 3 + 1) * N + n] = ay * inv;
            out[(b * 3 + 2) * N + n] = az * inv;
        }
    }
}

// ---------------------------------------------------------------------------
extern "C" void kernel_launch(void* const* d_in, const int* in_sizes, int n_in,
                              void* d_out, int out_size, void* d_ws, size_t ws_size,
                              hipStream_t stream)
{
    const float* p0   = (const float*)d_in[0];
    const float* p1   = (const float*)d_in[1];
    const float* wt   = (const float*)d_in[3];
    const int*   perm = (const int*)d_in[4];
    const float* w1   = (const float*)d_in[5];
    const float* b1   = (const float*)d_in[6];
    const float* gn1w = (const float*)d_in[7];
    const float* gn1b = (const float*)d_in[8];
    const float* w2   = (const float*)d_in[9];
    const float* b2   = (const float*)d_in[10];
    const float* gn2w = (const float*)d_in[11];
    const float* gn2b = (const float*)d_in[12];
    float* out = (float*)d_out;

    const int B = in_sizes[3] / 2;
    const int N = in_sizes[0] / (3 * B);

    // workspace layout
    char* ws = (char*)d_ws;
    float4* spts = (float4*)ws;               // B*2*4096 float4 (z-binned CSR)
    size_t off = (size_t)B * 2 * 4096 * sizeof(float4);
    float4* feat = (float4*)(ws + off);       off += (size_t)B * N * 32 * sizeof(float4);
    float4* newp = (float4*)(ws + off);       off += (size_t)B * N * sizeof(float4);
    float* stats1 = (float*)(ws + off);       off += (size_t)B * 14 * sizeof(float);
    float* stats2 = (float*)(ws + off);       off += (size_t)B * 16 * sizeof(float);
    int* starts = (int*)(ws + off);           // B*2*65 CSR offsets

    hipMemsetAsync(stats1, 0, (size_t)B * 30 * sizeof(float), stream);

    const float inv_cnt = 1.f / (8.f * (float)N * 32.f);

    gather_kernel<<<(B * N) / 256, 256, 0, stream>>>(p0, p1, wt, perm, newp, N);

    zbin_kernel<<<B * 2, 1024, 0, stream>>>(p0, p1, spts, starts, N);

    // one wave per query pair -> B*N waves -> B*N/4 blocks of 256 threads
    knn_kernel<<<(B * N) / 4, 256, 0, stream>>>(
        wt, spts, starts, feat, newp, N);

    moment_stats_kernel<<<B * 64, 256, 0, stream>>>(feat, stats1, N);

    conv2_pass_kernel<0><<<(B * N * 32) / 512, 256, 0, stream>>>(
        feat, w1, b1, gn1w, gn1b, stats1, w2, b2, gn2w, gn2b, stats2,
        newp, out, N, inv_cnt);

    conv2_pass_kernel<1><<<(B * N * 32) / 512, 256, 0, stream>>>(
        feat, w1, b1, gn1w, gn1b, stats1, w2, b2, gn2w, gn2b, stats2,
        newp, out, N, inv_cnt);
}

// Round 8
// 307.232 us; speedup vs baseline: 1.3124x; 1.1182x over previous
//
#include <hip/hip_runtime.h>
#include <math.h>

#define RQ 6               // per-lane queue depth (fallback path only)
constexpr int WRANKS = 768; // phase-1 rank window (12 chunks of 64)
constexpr int WCH = 12;

typedef __attribute__((ext_vector_type(8))) short s8v;    // 8 bf16 (4 VGPRs)
typedef __attribute__((ext_vector_type(4))) float f32x4;  // MFMA acc

__device__ inline unsigned short f2bf(float x) {          // RNE f32->bf16
    const unsigned int u = __float_as_uint(x);
    return (unsigned short)((u + 0x7FFFu + ((u >> 16) & 1u)) >> 16);
}

// N(0,1) quantiles at i/64, i=1..63. PERF-ONLY hint; CSR uses exact counts.
__constant__ float ZB[63] = {
    -2.1539f, -1.8627f, -1.6759f, -1.5341f, -1.4178f, -1.3180f, -1.2299f, -1.1503f,
    -1.0775f, -1.0100f, -0.9468f, -0.8871f, -0.8305f, -0.7764f, -0.7245f, -0.6745f,
    -0.6261f, -0.5791f, -0.5334f, -0.4888f, -0.4451f, -0.4023f, -0.3601f, -0.3186f,
    -0.2776f, -0.2372f, -0.1971f, -0.1573f, -0.1178f, -0.0784f, -0.0392f,  0.0000f,
     0.0392f,  0.0784f,  0.1178f,  0.1573f,  0.1971f,  0.2372f,  0.2776f,  0.3186f,
     0.3601f,  0.4023f,  0.4451f,  0.4888f,  0.5334f,  0.5791f,  0.6261f,  0.6745f,
     0.7245f,  0.7764f,  0.8305f,  0.8871f,  0.9468f,  1.0100f,  1.0775f,  1.1503f,
     1.2299f,  1.3180f,  1.4178f,  1.5341f,  1.6759f,  1.8627f,  2.1539f };

// ---------------------------------------------------------------------------
// K0: z-bin CSR build. One block per (b,list): count -> prefix -> scatter.
// ---------------------------------------------------------------------------
__global__ __launch_bounds__(1024) void zbin_kernel(
    const float* __restrict__ p0, const float* __restrict__ p1,
    float4* __restrict__ sp, int* __restrict__ starts, int N)
{
    __shared__ int cnt[64], off[64], cur[64];
    const int t = threadIdx.x;
    const int bl = blockIdx.x;                    // b*2 + list
    const int b = bl >> 1, list = bl & 1;
    const float* rb = (list ? p1 : p0) + (size_t)(b * 3) * N;
    if (t < 64) { cnt[t] = 0; cur[t] = 0; }
    __syncthreads();
    int mybin[4]; float mx[4], my[4], mz[4];
    for (int i = 0; i < 4; ++i) {
        const int idx = i * 1024 + t;
        const float z = rb[2 * N + idx];
        mx[i] = rb[idx]; my[i] = rb[N + idx]; mz[i] = z;
        int bin = 0;
#pragma unroll
        for (int s = 32; s; s >>= 1)
            if (bin + s <= 63 && z >= ZB[bin + s - 1]) bin += s;
        mybin[i] = bin;
        atomicAdd(&cnt[bin], 1);
    }
    __syncthreads();
    if (t < 64) {                                 // wave 0: exclusive prefix
        const int v = cnt[t];
        int x = v;
#pragma unroll
        for (int o = 1; o < 64; o <<= 1) {
            const int y = __shfl_up(x, o);
            if (t >= o) x += y;
        }
        off[t] = x - v;
        starts[bl * 65 + t] = x - v;
        if (t == 63) starts[bl * 65 + 64] = x;
    }
    __syncthreads();
    for (int i = 0; i < 4; ++i) {
        const int bin = mybin[i];
        const int pos = off[bin] + atomicAdd(&cur[bin], 1);
        sp[(size_t)bl * 4096 + pos] =
            make_float4(mx[i], my[i], mz[i],
                        fmaf(mx[i], mx[i], fmaf(my[i], my[i], mz[i] * mz[i])));
    }
}

// ---------------------------------------------------------------------------
// K0b: query gather. One thread per query; TLP hides the dependent gather
// latency (verified: FETCH_SIZE 7.39 -> 4.83 MB in knn).
// ---------------------------------------------------------------------------
__global__ __launch_bounds__(256) void gather_kernel(
    const float* __restrict__ p0, const float* __restrict__ p1,
    const float* __restrict__ wt, const int* __restrict__ perm,
    float4* __restrict__ newp, int N)
{
    const int q = blockIdx.x * 256 + threadIdx.x;
    const int b = q / N, n = q - b * N;
    const float wt0 = wt[b * 2];
    const int N0 = (int)(N * wt0);
    int j; const float* src;
    if (n < N0) { j = perm[(b * 2) * N + n];            src = p0; }
    else        { j = perm[(b * 2 + 1) * N + (n - N0)]; src = p1; }
    newp[q] = make_float4(src[(b * 3) * N + j], src[(b * 3 + 1) * N + j],
                          src[(b * 3 + 2) * N + j], 0.f);
}

// ---------------------------------------------------------------------------
// K1 helpers
// ---------------------------------------------------------------------------

// ballot-compact step: candidates with key<=T go to LDS slots (packed u64)
__device__ __forceinline__ void cpush(unsigned key, unsigned pos, unsigned Tu,
                                      bool valid, uint2* __restrict__ cc,
                                      int& cnt)
{
    const bool pred = valid && (key <= Tu);
    const unsigned long long bal = __ballot(pred);
    const unsigned below = __builtin_amdgcn_mbcnt_hi(
        (unsigned)(bal >> 32), __builtin_amdgcn_mbcnt_lo((unsigned)bal, 0u));
    const unsigned idx = (unsigned)cnt + below;
    if (pred && idx < 64u) cc[idx] = make_uint2(key, pos);
    cnt += (int)__popcll(bal);
}

// compaction scan over an arbitrary CSR range (expansion bins / remainders)
__device__ __forceinline__ void cscan(const float4* __restrict__ L,
                                      int bs, int be,
                                      float qx, float qy, float qz, float qq,
                                      unsigned Tu, uint2* __restrict__ cc,
                                      int& cnt, int lane)
{
    for (int p = bs; p < be; p += 64) {
        const int pos = p + lane;
        const float4 pc = L[min(pos, be - 1)];
        const float dt = fmaf(qz, pc.z, fmaf(qy, pc.y, qx * pc.x));
        const float d = fmaxf(fmaf(-2.f, dt, pc.w + qq), 0.f);
        cpush(__float_as_uint(d), (unsigned)pos, Tu, pos < be, cc, cnt);
    }
}

// single-list 64-wide bitonic sort of candidates, write top-kk.
// Selection order (key,pos) identical to the verified pop loop.
__device__ __forceinline__ void sort_write(
    const uint2* __restrict__ cc, int cnt,
    const float4* __restrict__ L, int kk, int obase,
    float qx, float qy, float qz, float4* __restrict__ feat, int lane)
{
    const uint2 v = cc[lane];
    unsigned vk = (lane < cnt) ? v.x : 0xFFFFFFFFu;
    unsigned vp = (lane < cnt) ? v.y : 0xFFFFFFFFu;
#pragma unroll
    for (int k2 = 2; k2 <= 64; k2 <<= 1) {
#pragma unroll
        for (int jj = k2 >> 1; jj; jj >>= 1) {
            const unsigned yk = __shfl_xor(vk, jj);
            const unsigned yp = __shfl_xor(vp, jj);
            const bool keepmin = (((lane & jj) == 0) == ((lane & k2) == 0));
            const bool lt = (vk < yk) || ((vk == yk) && (vp < yp));
            const bool sely = keepmin ? (!lt) : lt;
            vk = sely ? yk : vk;
            vp = sely ? yp : vp;
        }
    }
    if (lane < kk) {
        const float4 pc = L[vp & 4095u];
        const float rx = pc.x - qx, ry = pc.y - qy, rz = pc.z - qz;
        feat[obase + lane] =
            make_float4(rx, ry, rz, sqrtf(fmaf(rx, rx, fmaf(ry, ry, rz * rz))));
    }
}

// ---- fallback path (cnt>64, astronomically rare): full-list queue scan ----
__device__ __forceinline__ void qpush(unsigned (&kh)[RQ], unsigned (&kl)[RQ],
                                      unsigned key, unsigned pos)
{
    bool cb[RQ];
#pragma unroll
    for (int s = 0; s < RQ; ++s) cb[s] = key < kh[s];
#pragma unroll
    for (int s = RQ - 1; s >= 1; --s) {
        kh[s] = cb[s - 1] ? kh[s - 1] : (cb[s] ? key : kh[s]);
        kl[s] = cb[s - 1] ? kl[s - 1] : (cb[s] ? pos : kl[s]);
    }
    kh[0] = cb[0] ? key : kh[0];
    kl[0] = cb[0] ? pos : kl[0];
}

__device__ __forceinline__ void pop_extract(
    unsigned (&kh)[RQ], unsigned (&kl)[RQ], int kk,
    const float4* __restrict__ L, int obase,
    float qx, float qy, float qz, float4* __restrict__ feat, int lane)
{
    unsigned mwin = 0;
    for (int rr = 0; rr < kk; ++rr) {
        unsigned gg = kh[0];
#pragma unroll
        for (int off = 32; off; off >>= 1) gg = min(gg, __shfl_xor(gg, off));
        const bool tied = (kh[0] == gg);
        unsigned mc;
        const unsigned long long bal = __ballot(tied);
        if (bal & (bal - 1)) {
            mc = tied ? kl[0] : 0xFFFFFFFFu;
#pragma unroll
            for (int off = 32; off; off >>= 1) mc = min(mc, __shfl_xor(mc, off));
        } else {
            mc = __shfl(kl[0], (int)__ffsll((long long)bal) - 1);
        }
        const bool w = tied && (kl[0] == mc);
        if (lane == rr) mwin = mc;
#pragma unroll
        for (int s = 0; s < RQ - 1; ++s) {
            kh[s] = w ? kh[s + 1] : kh[s];
            kl[s] = w ? kl[s + 1] : kl[s];
        }
        kh[RQ - 1] = w ? 0xFFFFFFFFu : kh[RQ - 1];
        kl[RQ - 1] = w ? 0xFFFFFFFFu : kl[RQ - 1];
    }
    if (lane < kk) {
        const float4 pc = L[mwin & 4095u];
        const float rx = pc.x - qx, ry = pc.y - qy, rz = pc.z - qz;
        feat[obase + lane] =
            make_float4(rx, ry, rz, sqrtf(fmaf(rx, rx, fmaf(ry, ry, rz * rz))));
    }
}

__device__ __forceinline__ void fallback_full(
    const float4* __restrict__ L, int Npts, int kk, int obase,
    float qx, float qy, float qz, float qq,
    float4* __restrict__ feat, int lane)
{
    unsigned kh[RQ], kl[RQ];
#pragma unroll
    for (int s = 0; s < RQ; ++s) { kh[s] = 0xFFFFFFFFu; kl[s] = 0xFFFFFFFFu; }
    for (int p = 0; p < Npts; p += 64) {
        const int pos = p + lane;
        const float4 pc = L[min(pos, Npts - 1)];
        const float dt = fmaf(qz, pc.z, fmaf(qy, pc.y, qx * pc.x));
        const float d = fmaxf(fmaf(-2.f, dt, pc.w + qq), 0.f);
        const unsigned key = (pos < Npts) ? __float_as_uint(d) : 0xFFFFFFFFu;
        qpush(kh, kl, key, (unsigned)pos);
    }
    pop_extract(kh, kl, kk, L, obase, qx, qy, qz, feat, lane);
}

// ---------------------------------------------------------------------------
// K1: exact kNN. R8: ONE WAVE PER (b,list,n) TASK (was: one wave per query
// pair). Rationale: with the pop-loop gone, per-task cost is nearly
// kk-independent (T-sort/compaction/sort are constant-work), so the pairing
// no longer buys balance -- it only doubles the per-wave serial chain. The
// split halves per-wave latency (single-chain pass A / bitonic T / final
// sort), doubles wave count (65536 waves, 8 HW rounds amortize residual
// variance), and allows 8 waves/EU residency (launch_bounds(256,8),
// VGPR<=64) for a latency-bound kernel at 56% stall.
// Per-task math identical to R7 (verified): rank window W=768 (12 static
// chunks, 3-stage pipeline, keys in VGPRs), T = m_(kk) of lane mins via
// bitonic, register-sourced compaction, remainders + bin-edge-dz^2
// expansion, (key,pos) bitonic selection; cnt>64 -> exact fallback.
// ---------------------------------------------------------------------------
__global__ __launch_bounds__(256, 8) void knn_kernel(
    const float* __restrict__ wt,
    const float4* __restrict__ sp, const int* __restrict__ starts,
    float4* __restrict__ feat, const float4* __restrict__ newp, int N)
{
    __shared__ uint2 ccs[256];
    const int lane = threadIdx.x & 63;
    const int wv = threadIdx.x >> 6;
    const int gwave = (int)((blockIdx.x * 256 + threadIdx.x) >> 6); // task id
    const int bl = gwave / N;                     // b*2 + list
    const int n = gwave - bl * N;
    const int b = bl >> 1, list = bl & 1;
    const int q = b * N + n;

    uint2* __restrict__ cc = ccs + wv * 64;

    const float wt0 = __uint_as_float(__builtin_amdgcn_readfirstlane(
                          __float_as_uint(wt[b * 2])));
    const int k0 = (int)(32 * wt0);
    const int kk = list ? (32 - k0) : k0;         // in [8,24]

    const float4 qp = newp[q];                    // broadcast load
    const float qx = __uint_as_float(__builtin_amdgcn_readfirstlane(__float_as_uint(qp.x)));
    const float qy = __uint_as_float(__builtin_amdgcn_readfirstlane(__float_as_uint(qp.y)));
    const float qz = __uint_as_float(__builtin_amdgcn_readfirstlane(__float_as_uint(qp.z)));
    const float qq = qx * qx + qy * qy + qz * qz;

    const int stv = starts[bl * 65 + lane];       // lane j holds starts[j]

    // query bin via one ballot over the constant boundary table
    const float bv = (lane < 63) ? ZB[lane] : 3.0e38f;
    const int qbin = __popcll(__ballot(qz >= bv));    // 0..63

    const float4* L = sp + (size_t)bl * 4096;

    // rank window centered on the query bin's rank midpoint
    const int st = __shfl(stv, qbin);
    const int en = (qbin >= 63) ? N : __shfl(stv, qbin + 1);
    int s0 = ((st + en) >> 1) - WRANKS / 2;
    s0 = s0 < 0 ? 0 : (s0 > N - WRANKS ? N - WRANKS : s0);
    const int e0 = s0 + WRANKS;

    // ---- pass A: 12 static chunks, 3-stage pipeline, keys in VGPRs ----
    const float4* Lb = L + s0 + lane;
    unsigned kv[WCH];
    unsigned mn = 0xFFFFFFFFu;
    {
        float4 A[3], Bv[3];
#pragma unroll
        for (int c = 0; c < 3; ++c) A[c] = Lb[c << 6];
#pragma unroll
        for (int g = 0; g < 4; ++g) {
            if (g < 3) {
#pragma unroll
                for (int c = 0; c < 3; ++c) Bv[c] = Lb[(g * 3 + 3 + c) << 6];
            }
#pragma unroll
            for (int c = 0; c < 3; ++c) {
                const int ch = g * 3 + c;
                const float dt = fmaf(qz, A[c].z, fmaf(qy, A[c].y, qx * A[c].x));
                kv[ch] = __float_as_uint(fmaxf(fmaf(-2.f, dt, A[c].w + qq), 0.f));
                mn = min(mn, kv[ch]);
            }
            if (g < 3) {
#pragma unroll
                for (int c = 0; c < 3; ++c) A[c] = Bv[c];
            }
        }
    }

    // ---- T = m_(kk): single-chain wave bitonic sort of the 64 lane-mins ----
    unsigned x = mn;
#pragma unroll
    for (int k2 = 2; k2 <= 64; k2 <<= 1) {
#pragma unroll
        for (int jj = k2 >> 1; jj; jj >>= 1) {
            const unsigned y = __shfl_xor(x, jj);
            const bool keepmin = (((lane & jj) == 0) == ((lane & k2) == 0));
            x = keepmin ? min(x, y) : (x > y ? x : y);
        }
    }
    const unsigned Tu = (unsigned)__shfl((int)x, kk - 1);
    const float Tf = __uint_as_float(Tu);

    // ---- compaction from registers (no reload / recompute) ----
    int cnt = 0;
#pragma unroll
    for (int ch = 0; ch < WCH; ++ch)
        cpush(kv[ch], (unsigned)(s0 + (ch << 6) + lane), Tu, true, cc, cnt);

    // ---- outside the window: partial-bin remainders + bin-edge expansion ----
    {
        const int binL = __popcll(__ballot(stv <= s0)) - 1;     // bin of rank s0
        if (s0 > 0) {
            const int bs = __shfl(stv, binL);
            if (bs < s0) cscan(L, bs, s0, qx, qy, qz, qq, Tu, cc, cnt, lane);
            for (int jb = binL - 1; jb >= 0; --jb) {
                const float dz = qz - ZB[jb];
                if (dz * dz * 0.99999f > Tf) break;
                const int bs2 = __shfl(stv, jb);
                const int be2 = __shfl(stv, jb + 1);
                cscan(L, bs2, be2, qx, qy, qz, qq, Tu, cc, cnt, lane);
            }
        }
        if (e0 < N) {
            const int binR = __popcll(__ballot(stv <= e0)) - 1; // bin of rank e0
            const int re = (binR >= 63) ? N : __shfl(stv, binR + 1);
            if (e0 < re) cscan(L, e0, re, qx, qy, qz, qq, Tu, cc, cnt, lane);
            for (int jb = binR + 1; jb <= 63; ++jb) {
                const float dz = ZB[jb - 1] - qz;
                if (dz * dz * 0.99999f > Tf) break;
                const int bs2 = __shfl(stv, jb);
                const int be2 = (jb >= 63) ? N : __shfl(stv, jb + 1);
                cscan(L, bs2, be2, qx, qy, qz, qq, Tu, cc, cnt, lane);
            }
        }
    }

    // ---- finalize: single-chain sort, write top-kk (fallback if overflow) --
    const int obase = (q << 5) + (list ? k0 : 0);
    if (cnt <= 64)
        sort_write(cc, cnt, L, kk, obase, qx, qy, qz, feat, lane);
    else
        fallback_full(L, N, kk, obase, qx, qy, qz, qq, feat, lane);
}

// ---------------------------------------------------------------------------
// K2: per-sample feature moments (S=sum f [4], M=sum f f^T [10]).
// ---------------------------------------------------------------------------
__global__ __launch_bounds__(256) void moment_stats_kernel(
    const float4* __restrict__ feat, float* __restrict__ stats1, int N)
{
    const int t = threadIdx.x, lane = t & 63;
    const int bpb = 64;
    const int b = blockIdx.x / bpb;
    const int ppb = (N * 32) / bpb;
    const size_t base = (size_t)b * N * 32 + (size_t)(blockIdx.x % bpb) * ppb;
    float a[14];
#pragma unroll
    for (int i = 0; i < 14; ++i) a[i] = 0.f;
    for (int i = t; i < ppb; i += 256) {
        const float4 f = feat[base + i];
        a[0] += f.x; a[1] += f.y; a[2] += f.z; a[3] += f.w;
        a[4] = fmaf(f.x, f.x, a[4]);  a[5] = fmaf(f.x, f.y, a[5]);
        a[6] = fmaf(f.x, f.z, a[6]);  a[7] = fmaf(f.x, f.w, a[7]);
        a[8] = fmaf(f.y, f.y, a[8]);  a[9] = fmaf(f.y, f.z, a[9]);
        a[10] = fmaf(f.y, f.w, a[10]); a[11] = fmaf(f.z, f.z, a[11]);
        a[12] = fmaf(f.z, f.w, a[12]); a[13] = fmaf(f.w, f.w, a[13]);
    }
#pragma unroll
    for (int i = 0; i < 14; ++i) {
        float x = a[i];
#pragma unroll
        for (int o = 32; o; o >>= 1) x += __shfl_down(x, o);
        a[i] = x;
    }
    __shared__ float sm[14];
    if (t < 14) sm[t] = 0.f;
    __syncthreads();
    if (lane == 0) {
#pragma unroll
        for (int i = 0; i < 14; ++i) atomicAdd(&sm[i], a[i]);
    }
    __syncthreads();
    if (t < 14) atomicAdd(&stats1[b * 14 + t], sm[t]);
}

// ---------------------------------------------------------------------------
// K3/K4: conv1+gn1+relu -> bf16 h in LDS -> conv2 via MFMA 16x16x32
// ---------------------------------------------------------------------------
template <int MODE>
__global__ __launch_bounds__(256) void conv2_pass_kernel(
    const float4* __restrict__ feat,
    const float* __restrict__ w1, const float* __restrict__ b1,
    const float* __restrict__ gn1w, const float* __restrict__ gn1b,
    const float* __restrict__ stats1,
    const float* __restrict__ w2, const float* __restrict__ b2,
    const float* __restrict__ gn2w, const float* __restrict__ gn2b,
    float* __restrict__ stats2,
    const float4* __restrict__ newp, float* __restrict__ out,
    int N, float inv_cnt)
{
    const int t = threadIdx.x, lane = t & 63, wv = t >> 6;
    const int quad = lane >> 4, col = lane & 15;
    const int bpb = (N * 32) / 512;
    const int b = blockIdx.x / bpb;
    const int pblock = (blockIdx.x - b * bpb) * 512;
    const size_t pbase = (size_t)b * N * 32 + pblock + wv * 128;

    __shared__ float sfin[24];
    __shared__ float sacc[16];
    __shared__ unsigned short h_lds[512 * 40];
    __shared__ float ssc[512];

    if (t < 16) sacc[t] = 0.f;
    if (t < 4) {
        const float cnt = (float)(N * 32);
        const float* mm = stats1 + b * 14;
        const float S0 = mm[0], S1 = mm[1], S2 = mm[2], S3 = mm[3];
        float sum = 0.f, sq = 0.f;
        for (int cch = 0; cch < 8; ++cch) {
            const int cid = t * 8 + cch;
            const float4 w = ((const float4*)w1)[cid];
            const float bb = b1[cid];
            const float ws = w.x * S0 + w.y * S1 + w.z * S2 + w.w * S3;
            const float wMw =
                w.x * w.x * mm[4] + w.y * w.y * mm[8] + w.z * w.z * mm[11] +
                w.w * w.w * mm[13] +
                2.f * (w.x * w.y * mm[5] + w.x * w.z * mm[6] + w.x * w.w * mm[7] +
                       w.y * w.z * mm[9] + w.y * w.w * mm[10] + w.z * w.w * mm[12]);
            sum += cnt * bb + ws;
            sq += cnt * bb * bb + 2.f * bb * ws + wMw;
        }
        const float mu = sum * inv_cnt, var = sq * inv_cnt - mu * mu;
        sfin[2 * t] = mu; sfin[2 * t + 1] = rsqrtf(var + 1e-5f);
    }
    if (MODE == 1 && t >= 4 && t < 12) {
        const int g = t - 4;
        const float S = stats2[b * 16 + g], Q = stats2[b * 16 + 8 + g];
        const float mu = S * inv_cnt, var = Q * inv_cnt - mu * mu;
        sfin[8 + 2 * g] = mu; sfin[8 + 2 * g + 1] = rsqrtf(var + 1e-5f);
    }
    __syncthreads();

    const int c1 = lane & 31, pt = lane >> 5;
    const float4 w1r = ((const float4*)w1)[c1];
    const float b1c = b1[c1];
    const int g1 = c1 >> 3;
    const float sc1 = sfin[2 * g1 + 1] * gn1w[c1];
    const float sh1 = gn1b[c1] - sfin[2 * g1] * sc1;

    for (int it = 0; it < 64; ++it) {
        const size_t p = pbase + it * 2;
        const float4 f = feat[p + pt];
        const float y = b1c + w1r.x * f.x + w1r.y * f.y + w1r.z * f.z + w1r.w * f.w;
        const float h = fmaxf(0.f, fmaf(y, sc1, sh1));
        h_lds[(wv * 128 + it * 2 + pt) * 40 + c1] = f2bf(h);
    }

    s8v afr[4];
#pragma unroll
    for (int T = 0; T < 4; ++T) {
        const int row = T * 16 + col;
#pragma unroll
        for (int j2 = 0; j2 < 8; ++j2)
            afr[T][j2] = (short)f2bf(w2[row * 32 + quad * 8 + j2]);
    }

    float b2v[4][4], sc2v[4][4], sh2v[4][4];
#pragma unroll
    for (int T = 0; T < 4; ++T)
#pragma unroll
        for (int r4 = 0; r4 < 4; ++r4) {
            const int cch = T * 16 + quad * 4 + r4;
            b2v[T][r4] = b2[cch];
            if (MODE == 1) {
                const int g2 = cch >> 3;
                const float sc = sfin[8 + 2 * g2 + 1] * gn2w[cch];
                sc2v[T][r4] = sc;
                sh2v[T][r4] = gn2b[cch] - sfin[8 + 2 * g2] * sc + b2[cch] * sc;
            }
        }

    float gsum[4] = {0, 0, 0, 0}, gsq[4] = {0, 0, 0, 0};

    for (int pt16 = 0; pt16 < 8; ++pt16) {
        const int row = wv * 128 + pt16 * 16 + col;
        const s8v bfr = *(const s8v*)&h_lds[row * 40 + quad * 8];
        f32x4 acc[4];
#pragma unroll
        for (int T = 0; T < 4; ++T) {
            acc[T] = (f32x4){0.f, 0.f, 0.f, 0.f};
            acc[T] = __builtin_amdgcn_mfma_f32_16x16x32_bf16(afr[T], bfr, acc[T], 0, 0, 0);
        }
        if (MODE == 0) {
#pragma unroll
            for (int T = 0; T < 4; ++T)
#pragma unroll
                for (int r4 = 0; r4 < 4; ++r4) {
                    const float v = acc[T][r4] + b2v[T][r4];
                    gsum[T] += v;
                    gsq[T] = fmaf(v, v, gsq[T]);
                }
        } else {
            float s = -3.0e38f;
#pragma unroll
            for (int T = 0; T < 4; ++T)
#pragma unroll
                for (int r4 = 0; r4 < 4; ++r4)
                    s = fmaxf(s, fmaxf(0.f, fmaf(acc[T][r4], sc2v[T][r4], sh2v[T][r4])));
            s = fmaxf(s, __shfl_xor(s, 16));
            s = fmaxf(s, __shfl_xor(s, 32));
            if (quad == 0) ssc[wv * 128 + pt16 * 16 + col] = s;
        }
    }

    if (MODE == 0) {
#pragma unroll
        for (int T = 0; T < 4; ++T) {
#pragma unroll
            for (int o = 1; o < 16; o <<= 1) {
                gsum[T] += __shfl_xor(gsum[T], o);
                gsq[T] += __shfl_xor(gsq[T], o);
            }
            gsum[T] += __shfl_xor(gsum[T], 16);
            gsq[T] += __shfl_xor(gsq[T], 16);
        }
        if (lane == 0) {
#pragma unroll
            for (int T = 0; T < 4; ++T) {
                atomicAdd(&sacc[2 * T], gsum[T]);
                atomicAdd(&sacc[8 + 2 * T], gsq[T]);
            }
        }
        if (lane == 32) {
#pragma unroll
            for (int T = 0; T < 4; ++T) {
                atomicAdd(&sacc[2 * T + 1], gsum[T]);
                atomicAdd(&sacc[8 + 2 * T + 1], gsq[T]);
            }
        }
        __syncthreads();
        if (t < 16) atomicAdd(&stats2[b * 16 + t], sacc[t]);
    } else {
        __syncthreads();
        const int qi = t >> 4, sub = t & 15;
        const int qg = (b * N * 32 + pblock) / 32 + qi;
        const int n = qg - b * N;
        const float s0 = ssc[qi * 32 + sub], s1 = ssc[qi * 32 + 16 + sub];
        float mx = fmaxf(s0, s1);
#pragma unroll
        for (int o = 8; o; o >>= 1) mx = fmaxf(mx, __shfl_xor(mx, o));
        const float e0 = __expf(s0 - mx), e1 = __expf(s1 - mx);
        float ssum = e0 + e1;
#pragma unroll
        for (int o = 8; o; o >>= 1) ssum += __shfl_xor(ssum, o);
        const float4 qc = newp[qg];
        const float4 f0 = feat[(size_t)qg * 32 + sub];
        const float4 f1 = feat[(size_t)qg * 32 + 16 + sub];
        float ax = e0 * (qc.x + f0.x) + e1 * (qc.x + f1.x);
        float ay = e0 * (qc.y + f0.y) + e1 * (qc.y + f1.y);
        float az = e0 * (qc.z + f0.z) + e1 * (qc.z + f1.z);
#pragma unroll
        for (int o = 8; o; o >>= 1) {
            ax += __shfl_xor(ax, o);
            ay += __shfl_xor(ay, o);
            az += __shfl_xor(az, o);
        }
        if (sub == 0) {
            const float inv = 1.f / ssum;
            out[(b * 3 + 0) * N + n] = ax * inv;
            out[(b * 3 + 1) * N + n] = ay * inv;
            out[(b * 3 + 2) * N + n] = az * inv;
        }
    }
}

// ---------------------------------------------------------------------------
extern "C" void kernel_launch(void* const* d_in, const int* in_sizes, int n_in,
                              void* d_out, int out_size, void* d_ws, size_t ws_size,
                              hipStream_t stream)
{
    const float* p0   = (const float*)d_in[0];
    const float* p1   = (const float*)d_in[1];
    const float* wt   = (const float*)d_in[3];
    const int*   perm = (const int*)d_in[4];
    const float* w1   = (const float*)d_in[5];
    const float* b1   = (const float*)d_in[6];
    const float* gn1w = (const float*)d_in[7];
    const float* gn1b = (const float*)d_in[8];
    const float* w2   = (const float*)d_in[9];
    const float* b2   = (const float*)d_in[10];
    const float* gn2w = (const float*)d_in[11];
    const float* gn2b = (const float*)d_in[12];
    float* out = (float*)d_out;

    const int B = in_sizes[3] / 2;
    const int N = in_sizes[0] / (3 * B);

    // workspace layout
    char* ws = (char*)d_ws;
    float4* spts = (float4*)ws;               // B*2*4096 float4 (z-binned CSR)
    size_t off = (size_t)B * 2 * 4096 * sizeof(float4);
    float4* feat = (float4*)(ws + off);       off += (size_t)B * N * 32 * sizeof(float4);
    float4* newp = (float4*)(ws + off);       off += (size_t)B * N * sizeof(float4);
    float* stats1 = (float*)(ws + off);       off += (size_t)B * 14 * sizeof(float);
    float* stats2 = (float*)(ws + off);       off += (size_t)B * 16 * sizeof(float);
    int* starts = (int*)(ws + off);           // B*2*65 CSR offsets

    hipMemsetAsync(stats1, 0, (size_t)B * 30 * sizeof(float), stream);

    const float inv_cnt = 1.f / (8.f * (float)N * 32.f);

    gather_kernel<<<(B * N) / 256, 256, 0, stream>>>(p0, p1, wt, perm, newp, N);

    zbin_kernel<<<B * 2, 1024, 0, stream>>>(p0, p1, spts, starts, N);

    // one wave per (b,list,n) task -> B*2*N waves -> B*2*N/4 blocks of 256
    knn_kernel<<<(B * 2 * N) / 4, 256, 0, stream>>>(
        wt, spts, starts, feat, newp, N);

    moment_stats_kernel<<<B * 64, 256, 0, stream>>>(feat, stats1, N);

    conv2_pass_kernel<0><<<(B * N * 32) / 512, 256, 0, stream>>>(
        feat, w1, b1, gn1w, gn1b, stats1, w2, b2, gn2w, gn2b, stats2,
        newp, out, N, inv_cnt);

    conv2_pass_kernel<1><<<(B * N * 32) / 512, 256, 0, stream>>>(
        feat, w1, b1, gn1w, gn1b, stats1, w2, b2, gn2w, gn2b, stats2,
        newp, out, N, inv_cnt);
}

// Round 9
// 293.359 us; speedup vs baseline: 1.3744x; 1.0473x over previous
//
#include <hip/hip_runtime.h>
#include <math.h>

#define RQ 6               // per-lane queue depth (fallback path only)
constexpr int WRANKS = 768; // phase-1 rank window (12 chunks of 64)
constexpr int WCH = 12;

typedef __attribute__((ext_vector_type(8))) short s8v;    // 8 bf16 (4 VGPRs)
typedef __attribute__((ext_vector_type(4))) float f32x4;  // MFMA acc

__device__ inline unsigned short f2bf(float x) {          // RNE f32->bf16
    const unsigned int u = __float_as_uint(x);
    return (unsigned short)((u + 0x7FFFu + ((u >> 16) & 1u)) >> 16);
}

// N(0,1) quantiles at i/64, i=1..63. PERF-ONLY hint; CSR uses exact counts.
__constant__ float ZB[63] = {
    -2.1539f, -1.8627f, -1.6759f, -1.5341f, -1.4178f, -1.3180f, -1.2299f, -1.1503f,
    -1.0775f, -1.0100f, -0.9468f, -0.8871f, -0.8305f, -0.7764f, -0.7245f, -0.6745f,
    -0.6261f, -0.5791f, -0.5334f, -0.4888f, -0.4451f, -0.4023f, -0.3601f, -0.3186f,
    -0.2776f, -0.2372f, -0.1971f, -0.1573f, -0.1178f, -0.0784f, -0.0392f,  0.0000f,
     0.0392f,  0.0784f,  0.1178f,  0.1573f,  0.1971f,  0.2372f,  0.2776f,  0.3186f,
     0.3601f,  0.4023f,  0.4451f,  0.4888f,  0.5334f,  0.5791f,  0.6261f,  0.6745f,
     0.7245f,  0.7764f,  0.8305f,  0.8871f,  0.9468f,  1.0100f,  1.0775f,  1.1503f,
     1.2299f,  1.3180f,  1.4178f,  1.5341f,  1.6759f,  1.8627f,  2.1539f };

// ---------------------------------------------------------------------------
// K0: z-bin CSR build. One block per (b,list): count -> prefix -> scatter.
// ---------------------------------------------------------------------------
__global__ __launch_bounds__(1024) void zbin_kernel(
    const float* __restrict__ p0, const float* __restrict__ p1,
    float4* __restrict__ sp, int* __restrict__ starts, int N)
{
    __shared__ int cnt[64], off[64], cur[64];
    const int t = threadIdx.x;
    const int bl = blockIdx.x;                    // b*2 + list
    const int b = bl >> 1, list = bl & 1;
    const float* rb = (list ? p1 : p0) + (size_t)(b * 3) * N;
    if (t < 64) { cnt[t] = 0; cur[t] = 0; }
    __syncthreads();
    int mybin[4]; float mx[4], my[4], mz[4];
    for (int i = 0; i < 4; ++i) {
        const int idx = i * 1024 + t;
        const float z = rb[2 * N + idx];
        mx[i] = rb[idx]; my[i] = rb[N + idx]; mz[i] = z;
        int bin = 0;
#pragma unroll
        for (int s = 32; s; s >>= 1)
            if (bin + s <= 63 && z >= ZB[bin + s - 1]) bin += s;
        mybin[i] = bin;
        atomicAdd(&cnt[bin], 1);
    }
    __syncthreads();
    if (t < 64) {                                 // wave 0: exclusive prefix
        const int v = cnt[t];
        int x = v;
#pragma unroll
        for (int o = 1; o < 64; o <<= 1) {
            const int y = __shfl_up(x, o);
            if (t >= o) x += y;
        }
        off[t] = x - v;
        starts[bl * 65 + t] = x - v;
        if (t == 63) starts[bl * 65 + 64] = x;
    }
    __syncthreads();
    for (int i = 0; i < 4; ++i) {
        const int bin = mybin[i];
        const int pos = off[bin] + atomicAdd(&cur[bin], 1);
        sp[(size_t)bl * 4096 + pos] =
            make_float4(mx[i], my[i], mz[i],
                        fmaf(mx[i], mx[i], fmaf(my[i], my[i], mz[i] * mz[i])));
    }
}

// ---------------------------------------------------------------------------
// K0b: query gather. One thread per query; TLP hides the dependent gather
// latency (verified: FETCH_SIZE 7.39 -> 4.83 MB in knn).
// ---------------------------------------------------------------------------
__global__ __launch_bounds__(256) void gather_kernel(
    const float* __restrict__ p0, const float* __restrict__ p1,
    const float* __restrict__ wt, const int* __restrict__ perm,
    float4* __restrict__ newp, int N)
{
    const int q = blockIdx.x * 256 + threadIdx.x;
    const int b = q / N, n = q - b * N;
    const float wt0 = wt[b * 2];
    const int N0 = (int)(N * wt0);
    int j; const float* src;
    if (n < N0) { j = perm[(b * 2) * N + n];            src = p0; }
    else        { j = perm[(b * 2 + 1) * N + (n - N0)]; src = p1; }
    newp[q] = make_float4(src[(b * 3) * N + j], src[(b * 3 + 1) * N + j],
                          src[(b * 3 + 2) * N + j], 0.f);
}

// ---------------------------------------------------------------------------
// K1 helpers
// ---------------------------------------------------------------------------

// ballot-compact step: candidates with key<=T go to LDS slots (packed u64)
__device__ __forceinline__ void cpush(unsigned key, unsigned pos, unsigned Tu,
                                      bool valid, uint2* __restrict__ cc,
                                      int& cnt)
{
    const bool pred = valid && (key <= Tu);
    const unsigned long long bal = __ballot(pred);
    const unsigned below = __builtin_amdgcn_mbcnt_hi(
        (unsigned)(bal >> 32), __builtin_amdgcn_mbcnt_lo((unsigned)bal, 0u));
    const unsigned idx = (unsigned)cnt + below;
    if (pred && idx < 64u) cc[idx] = make_uint2(key, pos);
    cnt += (int)__popcll(bal);
}

// compaction scan over an arbitrary CSR range (expansion bins / remainders)
__device__ __forceinline__ void cscan(const float4* __restrict__ L,
                                      int bs, int be,
                                      float qx, float qy, float qz, float qq,
                                      unsigned Tu, uint2* __restrict__ cc,
                                      int& cnt, int lane)
{
    for (int p = bs; p < be; p += 64) {
        const int pos = p + lane;
        const float4 pc = L[min(pos, be - 1)];
        const float dt = fmaf(qz, pc.z, fmaf(qy, pc.y, qx * pc.x));
        const float d = fmaxf(fmaf(-2.f, dt, pc.w + qq), 0.f);
        cpush(__float_as_uint(d), (unsigned)pos, Tu, pos < be, cc, cnt);
    }
}

// single-list 64-wide bitonic sort of candidates, write top-kk.
// Selection order (key,pos) identical to the verified pop loop.
__device__ __forceinline__ void sort_write(
    const uint2* __restrict__ cc, int cnt,
    const float4* __restrict__ L, int kk, int obase,
    float qx, float qy, float qz, float4* __restrict__ feat, int lane)
{
    const uint2 v = cc[lane];
    unsigned vk = (lane < cnt) ? v.x : 0xFFFFFFFFu;
    unsigned vp = (lane < cnt) ? v.y : 0xFFFFFFFFu;
#pragma unroll
    for (int k2 = 2; k2 <= 64; k2 <<= 1) {
#pragma unroll
        for (int jj = k2 >> 1; jj; jj >>= 1) {
            const unsigned yk = __shfl_xor(vk, jj);
            const unsigned yp = __shfl_xor(vp, jj);
            const bool keepmin = (((lane & jj) == 0) == ((lane & k2) == 0));
            const bool lt = (vk < yk) || ((vk == yk) && (vp < yp));
            const bool sely = keepmin ? (!lt) : lt;
            vk = sely ? yk : vk;
            vp = sely ? yp : vp;
        }
    }
    if (lane < kk) {
        const float4 pc = L[vp & 4095u];
        const float rx = pc.x - qx, ry = pc.y - qy, rz = pc.z - qz;
        feat[obase + lane] =
            make_float4(rx, ry, rz, sqrtf(fmaf(rx, rx, fmaf(ry, ry, rz * rz))));
    }
}

// ---- fallback path (cnt>64, astronomically rare): full-list queue scan ----
__device__ __forceinline__ void qpush(unsigned (&kh)[RQ], unsigned (&kl)[RQ],
                                      unsigned key, unsigned pos)
{
    bool cb[RQ];
#pragma unroll
    for (int s = 0; s < RQ; ++s) cb[s] = key < kh[s];
#pragma unroll
    for (int s = RQ - 1; s >= 1; --s) {
        kh[s] = cb[s - 1] ? kh[s - 1] : (cb[s] ? key : kh[s]);
        kl[s] = cb[s - 1] ? kl[s - 1] : (cb[s] ? pos : kl[s]);
    }
    kh[0] = cb[0] ? key : kh[0];
    kl[0] = cb[0] ? pos : kl[0];
}

__device__ __forceinline__ void pop_extract(
    unsigned (&kh)[RQ], unsigned (&kl)[RQ], int kk,
    const float4* __restrict__ L, int obase,
    float qx, float qy, float qz, float4* __restrict__ feat, int lane)
{
    unsigned mwin = 0;
    for (int rr = 0; rr < kk; ++rr) {
        unsigned gg = kh[0];
#pragma unroll
        for (int off = 32; off; off >>= 1) gg = min(gg, __shfl_xor(gg, off));
        const bool tied = (kh[0] == gg);
        unsigned mc;
        const unsigned long long bal = __ballot(tied);
        if (bal & (bal - 1)) {
            mc = tied ? kl[0] : 0xFFFFFFFFu;
#pragma unroll
            for (int off = 32; off; off >>= 1) mc = min(mc, __shfl_xor(mc, off));
        } else {
            mc = __shfl(kl[0], (int)__ffsll((long long)bal) - 1);
        }
        const bool w = tied && (kl[0] == mc);
        if (lane == rr) mwin = mc;
#pragma unroll
        for (int s = 0; s < RQ - 1; ++s) {
            kh[s] = w ? kh[s + 1] : kh[s];
            kl[s] = w ? kl[s + 1] : kl[s];
        }
        kh[RQ - 1] = w ? 0xFFFFFFFFu : kh[RQ - 1];
        kl[RQ - 1] = w ? 0xFFFFFFFFu : kl[RQ - 1];
    }
    if (lane < kk) {
        const float4 pc = L[mwin & 4095u];
        const float rx = pc.x - qx, ry = pc.y - qy, rz = pc.z - qz;
        feat[obase + lane] =
            make_float4(rx, ry, rz, sqrtf(fmaf(rx, rx, fmaf(ry, ry, rz * rz))));
    }
}

__device__ __forceinline__ void fallback_full(
    const float4* __restrict__ L, int Npts, int kk, int obase,
    float qx, float qy, float qz, float qq,
    float4* __restrict__ feat, int lane)
{
    unsigned kh[RQ], kl[RQ];
#pragma unroll
    for (int s = 0; s < RQ; ++s) { kh[s] = 0xFFFFFFFFu; kl[s] = 0xFFFFFFFFu; }
    for (int p = 0; p < Npts; p += 64) {
        const int pos = p + lane;
        const float4 pc = L[min(pos, Npts - 1)];
        const float dt = fmaf(qz, pc.z, fmaf(qy, pc.y, qx * pc.x));
        const float d = fmaxf(fmaf(-2.f, dt, pc.w + qq), 0.f);
        const unsigned key = (pos < Npts) ? __float_as_uint(d) : 0xFFFFFFFFu;
        qpush(kh, kl, key, (unsigned)pos);
    }
    pop_extract(kh, kl, kk, L, obase, qx, qy, qz, feat, lane);
}

// ---------------------------------------------------------------------------
// K1: exact kNN. R9: ONE WAVE PER BLOCK (64 threads, grid = B*2*N blocks).
// R8 showed occupancy 48% / VALUBusy 60% with 256-thread blocks: block-slot
// replacement is gated by the slowest of 4 sibling waves (expansion-work
// variance wastes the other 3 slots). 1-wave blocks give wave-granular
// backfill; LDS/block = 512B, launch_bounds(64,8) keeps VGPR<=64 for 8
// waves/EU. Also: the 12 window-compaction ballots are now batched
// (independent ballots -> ILP; SALU prefix; independent writes) instead of
// a 12-deep serial cnt chain. Slot assignment and cnt identical.
// Per-task math identical to R8 (verified): rank window W=768 (12 static
// chunks, 3-stage pipeline, keys in VGPRs), T = m_(kk) of lane mins via
// bitonic, register-sourced compaction, remainders + bin-edge-dz^2
// expansion, (key,pos) bitonic selection; cnt>64 -> exact fallback.
// ---------------------------------------------------------------------------
__global__ __launch_bounds__(64, 8) void knn_kernel(
    const float* __restrict__ wt,
    const float4* __restrict__ sp, const int* __restrict__ starts,
    float4* __restrict__ feat, const float4* __restrict__ newp, int N)
{
    __shared__ uint2 cc[64];
    const int lane = threadIdx.x & 63;
    const int gwave = blockIdx.x;                 // task id
    const int bl = gwave / N;                     // b*2 + list
    const int n = gwave - bl * N;
    const int b = bl >> 1, list = bl & 1;
    const int q = b * N + n;

    const float wt0 = __uint_as_float(__builtin_amdgcn_readfirstlane(
                          __float_as_uint(wt[b * 2])));
    const int k0 = (int)(32 * wt0);
    const int kk = list ? (32 - k0) : k0;         // in [8,24]

    const float4 qp = newp[q];                    // broadcast load
    const float qx = __uint_as_float(__builtin_amdgcn_readfirstlane(__float_as_uint(qp.x)));
    const float qy = __uint_as_float(__builtin_amdgcn_readfirstlane(__float_as_uint(qp.y)));
    const float qz = __uint_as_float(__builtin_amdgcn_readfirstlane(__float_as_uint(qp.z)));
    const float qq = qx * qx + qy * qy + qz * qz;

    const int stv = starts[bl * 65 + lane];       // lane j holds starts[j]

    // query bin via one ballot over the constant boundary table
    const float bv = (lane < 63) ? ZB[lane] : 3.0e38f;
    const int qbin = __popcll(__ballot(qz >= bv));    // 0..63

    const float4* L = sp + (size_t)bl * 4096;

    // rank window centered on the query bin's rank midpoint
    const int st = __shfl(stv, qbin);
    const int en = (qbin >= 63) ? N : __shfl(stv, qbin + 1);
    int s0 = ((st + en) >> 1) - WRANKS / 2;
    s0 = s0 < 0 ? 0 : (s0 > N - WRANKS ? N - WRANKS : s0);
    const int e0 = s0 + WRANKS;

    // ---- pass A: 12 static chunks, 3-stage pipeline, keys in VGPRs ----
    const float4* Lb = L + s0 + lane;
    unsigned kv[WCH];
    unsigned mn = 0xFFFFFFFFu;
    {
        float4 A[3], Bv[3];
#pragma unroll
        for (int c = 0; c < 3; ++c) A[c] = Lb[c << 6];
#pragma unroll
        for (int g = 0; g < 4; ++g) {
            if (g < 3) {
#pragma unroll
                for (int c = 0; c < 3; ++c) Bv[c] = Lb[(g * 3 + 3 + c) << 6];
            }
#pragma unroll
            for (int c = 0; c < 3; ++c) {
                const int ch = g * 3 + c;
                const float dt = fmaf(qz, A[c].z, fmaf(qy, A[c].y, qx * A[c].x));
                kv[ch] = __float_as_uint(fmaxf(fmaf(-2.f, dt, A[c].w + qq), 0.f));
                mn = min(mn, kv[ch]);
            }
            if (g < 3) {
#pragma unroll
                for (int c = 0; c < 3; ++c) A[c] = Bv[c];
            }
        }
    }

    // ---- T = m_(kk): single-chain wave bitonic sort of the 64 lane-mins ----
    unsigned x = mn;
#pragma unroll
    for (int k2 = 2; k2 <= 64; k2 <<= 1) {
#pragma unroll
        for (int jj = k2 >> 1; jj; jj >>= 1) {
            const unsigned y = __shfl_xor(x, jj);
            const bool keepmin = (((lane & jj) == 0) == ((lane & k2) == 0));
            x = keepmin ? min(x, y) : (x > y ? x : y);
        }
    }
    const unsigned Tu = (unsigned)__shfl((int)x, kk - 1);
    const float Tf = __uint_as_float(Tu);

    // ---- window compaction from registers: BATCHED ballots (ILP) ----
    int cnt;
    {
        unsigned long long bals[WCH];
#pragma unroll
        for (int ch = 0; ch < WCH; ++ch)
            bals[ch] = __ballot(kv[ch] <= Tu);
        int base = 0;
#pragma unroll
        for (int ch = 0; ch < WCH; ++ch) {
            const unsigned below = __builtin_amdgcn_mbcnt_hi(
                (unsigned)(bals[ch] >> 32),
                __builtin_amdgcn_mbcnt_lo((unsigned)bals[ch], 0u));
            const unsigned idx = (unsigned)base + below;
            if ((kv[ch] <= Tu) && idx < 64u)
                cc[idx] = make_uint2(kv[ch], (unsigned)(s0 + (ch << 6) + lane));
            base += (int)__popcll(bals[ch]);
        }
        cnt = base;
    }

    // ---- outside the window: partial-bin remainders + bin-edge expansion ----
    {
        const int binL = __popcll(__ballot(stv <= s0)) - 1;     // bin of rank s0
        if (s0 > 0) {
            const int bs = __shfl(stv, binL);
            if (bs < s0) cscan(L, bs, s0, qx, qy, qz, qq, Tu, cc, cnt, lane);
            for (int jb = binL - 1; jb >= 0; --jb) {
                const float dz = qz - ZB[jb];
                if (dz * dz * 0.99999f > Tf) break;
                const int bs2 = __shfl(stv, jb);
                const int be2 = __shfl(stv, jb + 1);
                cscan(L, bs2, be2, qx, qy, qz, qq, Tu, cc, cnt, lane);
            }
        }
        if (e0 < N) {
            const int binR = __popcll(__ballot(stv <= e0)) - 1; // bin of rank e0
            const int re = (binR >= 63) ? N : __shfl(stv, binR + 1);
            if (e0 < re) cscan(L, e0, re, qx, qy, qz, qq, Tu, cc, cnt, lane);
            for (int jb = binR + 1; jb <= 63; ++jb) {
                const float dz = ZB[jb - 1] - qz;
                if (dz * dz * 0.99999f > Tf) break;
                const int bs2 = __shfl(stv, jb);
                const int be2 = (jb >= 63) ? N : __shfl(stv, jb + 1);
                cscan(L, bs2, be2, qx, qy, qz, qq, Tu, cc, cnt, lane);
            }
        }
    }

    // ---- finalize: single-chain sort, write top-kk (fallback if overflow) --
    const int obase = (q << 5) + (list ? k0 : 0);
    if (cnt <= 64)
        sort_write(cc, cnt, L, kk, obase, qx, qy, qz, feat, lane);
    else
        fallback_full(L, N, kk, obase, qx, qy, qz, qq, feat, lane);
}

// ---------------------------------------------------------------------------
// K2: per-sample feature moments (S=sum f [4], M=sum f f^T [10]).
// ---------------------------------------------------------------------------
__global__ __launch_bounds__(256) void moment_stats_kernel(
    const float4* __restrict__ feat, float* __restrict__ stats1, int N)
{
    const int t = threadIdx.x, lane = t & 63;
    const int bpb = 64;
    const int b = blockIdx.x / bpb;
    const int ppb = (N * 32) / bpb;
    const size_t base = (size_t)b * N * 32 + (size_t)(blockIdx.x % bpb) * ppb;
    float a[14];
#pragma unroll
    for (int i = 0; i < 14; ++i) a[i] = 0.f;
    for (int i = t; i < ppb; i += 256) {
        const float4 f = feat[base + i];
        a[0] += f.x; a[1] += f.y; a[2] += f.z; a[3] += f.w;
        a[4] = fmaf(f.x, f.x, a[4]);  a[5] = fmaf(f.x, f.y, a[5]);
        a[6] = fmaf(f.x, f.z, a[6]);  a[7] = fmaf(f.x, f.w, a[7]);
        a[8] = fmaf(f.y, f.y, a[8]);  a[9] = fmaf(f.y, f.z, a[9]);
        a[10] = fmaf(f.y, f.w, a[10]); a[11] = fmaf(f.z, f.z, a[11]);
        a[12] = fmaf(f.z, f.w, a[12]); a[13] = fmaf(f.w, f.w, a[13]);
    }
#pragma unroll
    for (int i = 0; i < 14; ++i) {
        float x = a[i];
#pragma unroll
        for (int o = 32; o; o >>= 1) x += __shfl_down(x, o);
        a[i] = x;
    }
    __shared__ float sm[14];
    if (t < 14) sm[t] = 0.f;
    __syncthreads();
    if (lane == 0) {
#pragma unroll
        for (int i = 0; i < 14; ++i) atomicAdd(&sm[i], a[i]);
    }
    __syncthreads();
    if (t < 14) atomicAdd(&stats1[b * 14 + t], sm[t]);
}

// ---------------------------------------------------------------------------
// K3/K4: conv1+gn1+relu -> bf16 h in LDS -> conv2 via MFMA 16x16x32
// ---------------------------------------------------------------------------
template <int MODE>
__global__ __launch_bounds__(256) void conv2_pass_kernel(
    const float4* __restrict__ feat,
    const float* __restrict__ w1, const float* __restrict__ b1,
    const float* __restrict__ gn1w, const float* __restrict__ gn1b,
    const float* __restrict__ stats1,
    const float* __restrict__ w2, const float* __restrict__ b2,
    const float* __restrict__ gn2w, const float* __restrict__ gn2b,
    float* __restrict__ stats2,
    const float4* __restrict__ newp, float* __restrict__ out,
    int N, float inv_cnt)
{
    const int t = threadIdx.x, lane = t & 63, wv = t >> 6;
    const int quad = lane >> 4, col = lane & 15;
    const int bpb = (N * 32) / 512;
    const int b = blockIdx.x / bpb;
    const int pblock = (blockIdx.x - b * bpb) * 512;
    const size_t pbase = (size_t)b * N * 32 + pblock + wv * 128;

    __shared__ float sfin[24];
    __shared__ float sacc[16];
    __shared__ unsigned short h_lds[512 * 40];
    __shared__ float ssc[512];

    if (t < 16) sacc[t] = 0.f;
    if (t < 4) {
        const float cnt = (float)(N * 32);
        const float* mm = stats1 + b * 14;
        const float S0 = mm[0], S1 = mm[1], S2 = mm[2], S3 = mm[3];
        float sum = 0.f, sq = 0.f;
        for (int cch = 0; cch < 8; ++cch) {
            const int cid = t * 8 + cch;
            const float4 w = ((const float4*)w1)[cid];
            const float bb = b1[cid];
            const float ws = w.x * S0 + w.y * S1 + w.z * S2 + w.w * S3;
            const float wMw =
                w.x * w.x * mm[4] + w.y * w.y * mm[8] + w.z * w.z * mm[11] +
                w.w * w.w * mm[13] +
                2.f * (w.x * w.y * mm[5] + w.x * w.z * mm[6] + w.x * w.w * mm[7] +
                       w.y * w.z * mm[9] + w.y * w.w * mm[10] + w.z * w.w * mm[12]);
            sum += cnt * bb + ws;
            sq += cnt * bb * bb + 2.f * bb * ws + wMw;
        }
        const float mu = sum * inv_cnt, var = sq * inv_cnt - mu * mu;
        sfin[2 * t] = mu; sfin[2 * t + 1] = rsqrtf(var + 1e-5f);
    }
    if (MODE == 1 && t >= 4 && t < 12) {
        const int g = t - 4;
        const float S = stats2[b * 16 + g], Q = stats2[b * 16 + 8 + g];
        const float mu = S * inv_cnt, var = Q * inv_cnt - mu * mu;
        sfin[8 + 2 * g] = mu; sfin[8 + 2 * g + 1] = rsqrtf(var + 1e-5f);
    }
    __syncthreads();

    const int c1 = lane & 31, pt = lane >> 5;
    const float4 w1r = ((const float4*)w1)[c1];
    const float b1c = b1[c1];
    const int g1 = c1 >> 3;
    const float sc1 = sfin[2 * g1 + 1] * gn1w[c1];
    const float sh1 = gn1b[c1] - sfin[2 * g1] * sc1;

    for (int it = 0; it < 64; ++it) {
        const size_t p = pbase + it * 2;
        const float4 f = feat[p + pt];
        const float y = b1c + w1r.x * f.x + w1r.y * f.y + w1r.z * f.z + w1r.w * f.w;
        const float h = fmaxf(0.f, fmaf(y, sc1, sh1));
        h_lds[(wv * 128 + it * 2 + pt) * 40 + c1] = f2bf(h);
    }

    s8v afr[4];
#pragma unroll
    for (int T = 0; T < 4; ++T) {
        const int row = T * 16 + col;
#pragma unroll
        for (int j2 = 0; j2 < 8; ++j2)
            afr[T][j2] = (short)f2bf(w2[row * 32 + quad * 8 + j2]);
    }

    float b2v[4][4], sc2v[4][4], sh2v[4][4];
#pragma unroll
    for (int T = 0; T < 4; ++T)
#pragma unroll
        for (int r4 = 0; r4 < 4; ++r4) {
            const int cch = T * 16 + quad * 4 + r4;
            b2v[T][r4] = b2[cch];
            if (MODE == 1) {
                const int g2 = cch >> 3;
                const float sc = sfin[8 + 2 * g2 + 1] * gn2w[cch];
                sc2v[T][r4] = sc;
                sh2v[T][r4] = gn2b[cch] - sfin[8 + 2 * g2] * sc + b2[cch] * sc;
            }
        }

    float gsum[4] = {0, 0, 0, 0}, gsq[4] = {0, 0, 0, 0};

    for (int pt16 = 0; pt16 < 8; ++pt16) {
        const int row = wv * 128 + pt16 * 16 + col;
        const s8v bfr = *(const s8v*)&h_lds[row * 40 + quad * 8];
        f32x4 acc[4];
#pragma unroll
        for (int T = 0; T < 4; ++T) {
            acc[T] = (f32x4){0.f, 0.f, 0.f, 0.f};
            acc[T] = __builtin_amdgcn_mfma_f32_16x16x32_bf16(afr[T], bfr, acc[T], 0, 0, 0);
        }
        if (MODE == 0) {
#pragma unroll
            for (int T = 0; T < 4; ++T)
#pragma unroll
                for (int r4 = 0; r4 < 4; ++r4) {
                    const float v = acc[T][r4] + b2v[T][r4];
                    gsum[T] += v;
                    gsq[T] = fmaf(v, v, gsq[T]);
                }
        } else {
            float s = -3.0e38f;
#pragma unroll
            for (int T = 0; T < 4; ++T)
#pragma unroll
                for (int r4 = 0; r4 < 4; ++r4)
                    s = fmaxf(s, fmaxf(0.f, fmaf(acc[T][r4], sc2v[T][r4], sh2v[T][r4])));
            s = fmaxf(s, __shfl_xor(s, 16));
            s = fmaxf(s, __shfl_xor(s, 32));
            if (quad == 0) ssc[wv * 128 + pt16 * 16 + col] = s;
        }
    }

    if (MODE == 0) {
#pragma unroll
        for (int T = 0; T < 4; ++T) {
#pragma unroll
            for (int o = 1; o < 16; o <<= 1) {
                gsum[T] += __shfl_xor(gsum[T], o);
                gsq[T] += __shfl_xor(gsq[T], o);
            }
            gsum[T] += __shfl_xor(gsum[T], 16);
            gsq[T] += __shfl_xor(gsq[T], 16);
        }
        if (lane == 0) {
#pragma unroll
            for (int T = 0; T < 4; ++T) {
                atomicAdd(&sacc[2 * T], gsum[T]);
                atomicAdd(&sacc[8 + 2 * T], gsq[T]);
            }
        }
        if (lane == 32) {
#pragma unroll
            for (int T = 0; T < 4; ++T) {
                atomicAdd(&sacc[2 * T + 1], gsum[T]);
                atomicAdd(&sacc[8 + 2 * T + 1], gsq[T]);
            }
        }
        __syncthreads();
        if (t < 16) atomicAdd(&stats2[b * 16 + t], sacc[t]);
    } else {
        __syncthreads();
        const int qi = t >> 4, sub = t & 15;
        const int qg = (b * N * 32 + pblock) / 32 + qi;
        const int n = qg - b * N;
        const float s0 = ssc[qi * 32 + sub], s1 = ssc[qi * 32 + 16 + sub];
        float mx = fmaxf(s0, s1);
#pragma unroll
        for (int o = 8; o; o >>= 1) mx = fmaxf(mx, __shfl_xor(mx, o));
        const float e0 = __expf(s0 - mx), e1 = __expf(s1 - mx);
        float ssum = e0 + e1;
#pragma unroll
        for (int o = 8; o; o >>= 1) ssum += __shfl_xor(ssum, o);
        const float4 qc = newp[qg];
        const float4 f0 = feat[(size_t)qg * 32 + sub];
        const float4 f1 = feat[(size_t)qg * 32 + 16 + sub];
        float ax = e0 * (qc.x + f0.x) + e1 * (qc.x + f1.x);
        float ay = e0 * (qc.y + f0.y) + e1 * (qc.y + f1.y);
        float az = e0 * (qc.z + f0.z) + e1 * (qc.z + f1.z);
#pragma unroll
        for (int o = 8; o; o >>= 1) {
            ax += __shfl_xor(ax, o);
            ay += __shfl_xor(ay, o);
            az += __shfl_xor(az, o);
        }
        if (sub == 0) {
            const float inv = 1.f / ssum;
            out[(b * 3 + 0) * N + n] = ax * inv;
            out[(b * 3 + 1) * N + n] = ay * inv;
            out[(b * 3 + 2) * N + n] = az * inv;
        }
    }
}

// ---------------------------------------------------------------------------
extern "C" void kernel_launch(void* const* d_in, const int* in_sizes, int n_in,
                              void* d_out, int out_size, void* d_ws, size_t ws_size,
                              hipStream_t stream)
{
    const float* p0   = (const float*)d_in[0];
    const float* p1   = (const float*)d_in[1];
    const float* wt   = (const float*)d_in[3];
    const int*   perm = (const int*)d_in[4];
    const float* w1   = (const float*)d_in[5];
    const float* b1   = (const float*)d_in[6];
    const float* gn1w = (const float*)d_in[7];
    const float* gn1b = (const float*)d_in[8];
    const float* w2   = (const float*)d_in[9];
    const float* b2   = (const float*)d_in[10];
    const float* gn2w = (const float*)d_in[11];
    const float* gn2b = (const float*)d_in[12];
    float* out = (float*)d_out;

    const int B = in_sizes[3] / 2;
    const int N = in_sizes[0] / (3 * B);

    // workspace layout
    char* ws = (char*)d_ws;
    float4* spts = (float4*)ws;               // B*2*4096 float4 (z-binned CSR)
    size_t off = (size_t)B * 2 * 4096 * sizeof(float4);
    float4* feat = (float4*)(ws + off);       off += (size_t)B * N * 32 * sizeof(float4);
    float4* newp = (float4*)(ws + off);       off += (size_t)B * N * sizeof(float4);
    float* stats1 = (float*)(ws + off);       off += (size_t)B * 14 * sizeof(float);
    float* stats2 = (float*)(ws + off);       off += (size_t)B * 16 * sizeof(float);
    int* starts = (int*)(ws + off);           // B*2*65 CSR offsets

    hipMemsetAsync(stats1, 0, (size_t)B * 30 * sizeof(float), stream);

    const float inv_cnt = 1.f / (8.f * (float)N * 32.f);

    gather_kernel<<<(B * N) / 256, 256, 0, stream>>>(p0, p1, wt, perm, newp, N);

    zbin_kernel<<<B * 2, 1024, 0, stream>>>(p0, p1, spts, starts, N);

    // one wave per (b,list,n) task -> B*2*N single-wave blocks of 64 threads
    knn_kernel<<<B * 2 * N, 64, 0, stream>>>(
        wt, spts, starts, feat, newp, N);

    moment_stats_kernel<<<B * 64, 256, 0, stream>>>(feat, stats1, N);

    conv2_pass_kernel<0><<<(B * N * 32) / 512, 256, 0, stream>>>(
        feat, w1, b1, gn1w, gn1b, stats1, w2, b2, gn2w, gn2b, stats2,
        newp, out, N, inv_cnt);

    conv2_pass_kernel<1><<<(B * N * 32) / 512, 256, 0, stream>>>(
        feat, w1, b1, gn1w, gn1b, stats1, w2, b2, gn2w, gn2b, stats2,
        newp, out, N, inv_cnt);
}